// Round 2
// baseline (2242.233 us; speedup 1.0000x reference)
//
#include <hip/hip_runtime.h>
#include <math.h>

#define NTOK 4097
#define CDIM 512
#define EPS_LN 1e-5f

// ---------------- concat: h0 = [cls; x] ----------------
__global__ void concat_kernel(const float* __restrict__ x, const float* __restrict__ cls,
                              float* __restrict__ h0, int total){
    int idx = blockIdx.x * 256 + threadIdx.x;
    if (idx >= total) return;
    int n = idx >> 9;         // /512
    int c = idx & 511;
    h0[idx] = (n == 0) ? cls[c] : x[(size_t)(n - 1) * CDIM + c];
}

// ---------------- layernorm (no bias), per token row of 512 ----------------
__global__ __launch_bounds__(256) void ln_kernel(const float* __restrict__ in,
                                                 const float* __restrict__ g,
                                                 float* __restrict__ out){
    int n = blockIdx.x;
    const float* row = in + (size_t)n * CDIM;
    int t = threadIdx.x;
    float x0 = row[t], x1 = row[t + 256];
    float s = x0 + x1, q = x0 * x0 + x1 * x1;
    for (int o = 32; o > 0; o >>= 1) { s += __shfl_down(s, o); q += __shfl_down(q, o); }
    __shared__ float rs[4], rq[4], mv[2];
    int wid = t >> 6;
    if ((t & 63) == 0) { rs[wid] = s; rq[wid] = q; }
    __syncthreads();
    if (t == 0) {
        float S = rs[0] + rs[1] + rs[2] + rs[3];
        float Q = rq[0] + rq[1] + rq[2] + rq[3];
        float m = S / 512.0f;
        float v = Q / 512.0f - m * m;
        mv[0] = m; mv[1] = rsqrtf(v + EPS_LN);
    }
    __syncthreads();
    float m = mv[0], r = mv[1];
    float* orow = out + (size_t)n * CDIM;
    orow[t]       = (x0 - m) * r * g[t];
    orow[t + 256] = (x1 - m) * r * g[t + 256];
}

// ---------------- generic fp32 GEMM: C[M,N] = A[M,512] * B[N,512]^T (+bias)(+resid) ----------------
__global__ __launch_bounds__(256) void gemm_abt(const float* __restrict__ A,
                                                const float* __restrict__ B,
                                                const float* __restrict__ resid,
                                                const float* __restrict__ bias,
                                                float* __restrict__ C, int M, int N){
    __shared__ float As[16][68];
    __shared__ float Bs[16][68];
    int t = threadIdx.x;
    int tx = t & 15, ty = t >> 4;
    int bm = blockIdx.x, bn = blockIdx.y;
    float acc[4][4] = {};
    int rl = t >> 2;
    int c4 = t & 3;
    int arow = bm * 64 + rl;
    int brow = bn * 64 + rl;
    for (int k0 = 0; k0 < 512; k0 += 16) {
        __syncthreads();
        float4 a4 = make_float4(0.f, 0.f, 0.f, 0.f);
        float4 b4 = make_float4(0.f, 0.f, 0.f, 0.f);
        if (arow < M) a4 = *(const float4*)(A + (size_t)arow * 512 + k0 + c4 * 4);
        if (brow < N) b4 = *(const float4*)(B + (size_t)brow * 512 + k0 + c4 * 4);
        As[c4 * 4 + 0][rl] = a4.x; As[c4 * 4 + 1][rl] = a4.y;
        As[c4 * 4 + 2][rl] = a4.z; As[c4 * 4 + 3][rl] = a4.w;
        Bs[c4 * 4 + 0][rl] = b4.x; Bs[c4 * 4 + 1][rl] = b4.y;
        Bs[c4 * 4 + 2][rl] = b4.z; Bs[c4 * 4 + 3][rl] = b4.w;
        __syncthreads();
        #pragma unroll
        for (int kk = 0; kk < 16; kk++) {
            float4 av = *(const float4*)(&As[kk][ty * 4]);
            float4 bv = *(const float4*)(&Bs[kk][tx * 4]);
            acc[0][0] += av.x * bv.x; acc[0][1] += av.x * bv.y; acc[0][2] += av.x * bv.z; acc[0][3] += av.x * bv.w;
            acc[1][0] += av.y * bv.x; acc[1][1] += av.y * bv.y; acc[1][2] += av.y * bv.z; acc[1][3] += av.y * bv.w;
            acc[2][0] += av.z * bv.x; acc[2][1] += av.z * bv.y; acc[2][2] += av.z * bv.z; acc[2][3] += av.z * bv.w;
            acc[3][0] += av.w * bv.x; acc[3][1] += av.w * bv.y; acc[3][2] += av.w * bv.z; acc[3][3] += av.w * bv.w;
        }
    }
    int row0 = bm * 64 + ty * 4;
    int col0 = bn * 64 + tx * 4;
    for (int i = 0; i < 4; i++) {
        int row = row0 + i;
        if (row >= M) continue;
        float* crow = C + (size_t)row * N;
        const float* rrow = resid ? (resid + (size_t)row * N) : nullptr;
        for (int j = 0; j < 4; j++) {
            int col = col0 + j;
            if (col >= N) continue;
            float v = acc[i][j];
            if (bias) v += bias[col];
            if (rrow) v += rrow[col];
            crow[col] = v;
        }
    }
}

// ---------------- layer-1 flash attention (full, streaming softmax) ----------------
// qkv row layout per token: [0:512]=Q, [512:1024]=K, [1024:1536]=V; head h occupies h*64..h*64+63
__global__ __launch_bounds__(256) void flash1(const float* __restrict__ qkv, float* __restrict__ out){
    const int h  = blockIdx.y;
    const int qb = blockIdx.x;
    const int t  = threadIdx.x;
    __shared__ float Qs[32][68];
    __shared__ float Ks[64][68];
    __shared__ float Vs[64][68];
    __shared__ float Ps[32][68];
    // load Q tile (32 x 64) as float4
    #pragma unroll
    for (int i = 0; i < 2; i++) {
        int lin = t + i * 256;            // float4 index, 512 total
        int r = lin >> 4, d4 = lin & 15;
        int tok = qb * 32 + r;
        float4 q = make_float4(0.f, 0.f, 0.f, 0.f);
        if (tok < NTOK) q = *(const float4*)(qkv + (size_t)tok * 1536 + h * 64 + d4 * 4);
        *(float4*)(&Qs[r][d4 * 4]) = q;
    }
    const int r  = t >> 3;
    const int cg = t & 7;
    float m = -INFINITY, l = 0.f;
    float acc[8] = {0.f, 0.f, 0.f, 0.f, 0.f, 0.f, 0.f, 0.f};
    for (int kb = 0; kb < 65; ++kb) {
        __syncthreads();   // previous iteration's PV readers done
        // load K,V tile (64 x 64 each)
        #pragma unroll
        for (int i = 0; i < 4; i++) {
            int lin = t + i * 256;        // float4 index, 1024 total
            int rr = lin >> 4, d4 = lin & 15;
            int tok = kb * 64 + rr;
            float4 kv4 = make_float4(0.f, 0.f, 0.f, 0.f);
            float4 vv4 = make_float4(0.f, 0.f, 0.f, 0.f);
            if (tok < NTOK) {
                const float* base = qkv + (size_t)tok * 1536 + h * 64 + d4 * 4;
                kv4 = *(const float4*)(base + 512);
                vv4 = *(const float4*)(base + 1024);
            }
            *(float4*)(&Ks[rr][d4 * 4]) = kv4;
            *(float4*)(&Vs[rr][d4 * 4]) = vv4;
        }
        __syncthreads();
        // scores: thread handles row r, cols cg*8 .. cg*8+7
        float sc[8];
        #pragma unroll
        for (int cc = 0; cc < 8; cc++) sc[cc] = 0.f;
        #pragma unroll
        for (int kk = 0; kk < 16; kk++) {
            float4 q4 = *(const float4*)(&Qs[r][kk * 4]);
            #pragma unroll
            for (int cc = 0; cc < 8; cc++) {
                float4 k4 = *(const float4*)(&Ks[cg * 8 + cc][kk * 4]);
                sc[cc] += q4.x * k4.x + q4.y * k4.y + q4.z * k4.z + q4.w * k4.w;
            }
        }
        float tm = -INFINITY;
        #pragma unroll
        for (int cc = 0; cc < 8; cc++) {
            int key = kb * 64 + cg * 8 + cc;
            sc[cc] = (key < NTOK) ? sc[cc] * 0.125f : -INFINITY;
            tm = fmaxf(tm, sc[cc]);
        }
        for (int o = 1; o < 8; o <<= 1) tm = fmaxf(tm, __shfl_xor(tm, o));
        float mn = fmaxf(m, tm);
        float alpha = __expf(m - mn);
        float psum = 0.f;
        #pragma unroll
        for (int cc = 0; cc < 8; cc++) {
            float p = __expf(sc[cc] - mn);
            Ps[r][cg * 8 + cc] = p;
            psum += p;
        }
        for (int o = 1; o < 8; o <<= 1) psum += __shfl_xor(psum, o);
        l = l * alpha + psum;
        m = mn;
        #pragma unroll
        for (int j = 0; j < 8; j++) acc[j] *= alpha;
        __syncthreads();   // Ps visible
        // PV: o[r][cg*8 + 0..7] += sum_c P[r][c] * V[c][*]
        #pragma unroll 16
        for (int c = 0; c < 64; c++) {
            float pv = Ps[r][c];
            float4 v0 = *(const float4*)(&Vs[c][cg * 8]);
            float4 v1 = *(const float4*)(&Vs[c][cg * 8 + 4]);
            acc[0] += pv * v0.x; acc[1] += pv * v0.y; acc[2] += pv * v0.z; acc[3] += pv * v0.w;
            acc[4] += pv * v1.x; acc[5] += pv * v1.y; acc[6] += pv * v1.z; acc[7] += pv * v1.w;
        }
    }
    int tok = qb * 32 + r;
    if (tok < NTOK) {
        float inv = 1.0f / l;
        float* o = out + (size_t)tok * CDIM + h * 64 + cg * 8;
        #pragma unroll
        for (int j = 0; j < 8; j++) o[j] = acc[j] * inv;
    }
}

// ---------------- layer-1 depthwise conv residual add (into attn buffer) ----------------
__global__ void convres_kernel(const float* __restrict__ qkv, const float* __restrict__ rk,
                               float* __restrict__ attn){
    int idx = blockIdx.x * 256 + threadIdx.x;
    if (idx >= NTOK * CDIM) return;
    int n = idx >> 9, hd = idx & 511, h = hd >> 6;
    float a = attn[idx];
    const float* kr = rk + h * 33;
    #pragma unroll
    for (int k = 0; k < 33; k++) {
        int mm = n + k - 16;
        if (mm >= 0 && mm < NTOK)
            a += qkv[(size_t)mm * 1536 + 1024 + hd] * kr[k];
    }
    attn[idx] = a;
}

// ---------------- layer 2: q row 0 ----------------
__global__ void qrow_kernel(const float* __restrict__ ln2, const float* __restrict__ wqkv,
                            float* __restrict__ q2){
    int j = blockIdx.x;        // 512 outputs
    int lane = threadIdx.x;    // 64
    const float* w = wqkv + (size_t)j * 512;
    float s = 0.f;
    for (int k = lane; k < 512; k += 64) s += ln2[k] * w[k];
    for (int o = 32; o > 0; o >>= 1) s += __shfl_down(s, o);
    if (lane == 0) q2[j] = s;
}

// ---------------- layer 2: score row 0 (all heads) ----------------
__global__ void srow_kernel(const float* __restrict__ q2, const float* __restrict__ kv2,
                            float* __restrict__ srow){
    int mm = blockIdx.x * 256 + threadIdx.x;
    int h = blockIdx.y;
    if (mm >= NTOK) return;
    const float* q = q2 + h * 64;
    const float* k = kv2 + (size_t)mm * 1024 + h * 64;
    float s = 0.f;
    #pragma unroll
    for (int d = 0; d < 64; d++) s += q[d] * k[d];
    srow[(size_t)h * NTOK + mm] = s * 0.125f;
}

// ---------------- layer 2: softmax over score row ----------------
__global__ __launch_bounds__(256) void softmax_row(float* __restrict__ srow, float* __restrict__ Lout){
    int h = blockIdx.x, t = threadIdx.x;
    float* s = srow + (size_t)h * NTOK;
    __shared__ float red[4];
    float mx = -INFINITY;
    for (int i = t; i < NTOK; i += 256) mx = fmaxf(mx, s[i]);
    for (int o = 32; o > 0; o >>= 1) mx = fmaxf(mx, __shfl_xor(mx, o));
    if ((t & 63) == 0) red[t >> 6] = mx;
    __syncthreads();
    mx = fmaxf(fmaxf(red[0], red[1]), fmaxf(red[2], red[3]));
    __syncthreads();
    float sum = 0.f;
    for (int i = t; i < NTOK; i += 256) { float p = __expf(s[i] - mx); s[i] = p; sum += p; }
    for (int o = 32; o > 0; o >>= 1) sum += __shfl_xor(sum, o);
    if ((t & 63) == 0) red[t >> 6] = sum;
    __syncthreads();
    if (t == 0) Lout[h] = red[0] + red[1] + red[2] + red[3];
}

// ---------------- layer 2: o2[hd] = sum_m p[h][m] * v2[m][hd] / L[h] ----------------
__global__ __launch_bounds__(256) void pv_row(const float* __restrict__ srow, const float* __restrict__ kv2,
                                              const float* __restrict__ L, float* __restrict__ o2){
    int hd = blockIdx.x;       // 512
    int h = hd >> 6;
    int t = threadIdx.x;
    const float* p = srow + (size_t)h * NTOK;
    const float* v = kv2 + 512 + hd;
    float s = 0.f;
    for (int i = t; i < NTOK; i += 256) s += p[i] * v[(size_t)i * 1024];
    for (int o = 32; o > 0; o >>= 1) s += __shfl_down(s, o);
    __shared__ float red[4];
    if ((t & 63) == 0) red[t >> 6] = s;
    __syncthreads();
    if (t == 0) o2[hd] = (red[0] + red[1] + red[2] + red[3]) / L[h];
}

// ---------------- layer 2: conv at position 0, add into o2 ----------------
__global__ void conv0_kernel(const float* __restrict__ kv2, const float* __restrict__ rk,
                             float* __restrict__ o2){
    int hd = threadIdx.x;      // 512
    int h = hd >> 6;
    float a = o2[hd];
    #pragma unroll
    for (int k = 16; k < 33; k++)
        a += kv2[(size_t)(k - 16) * 1024 + 512 + hd] * rk[h * 33 + k];
    o2[hd] = a;
}

// ---------------- final: proj row 0 + residual + layernorm ----------------
__global__ __launch_bounds__(512) void final_kernel(const float* __restrict__ h1, const float* __restrict__ o2,
                                                    const float* __restrict__ wproj, const float* __restrict__ bproj,
                                                    const float* __restrict__ fcg, float* __restrict__ out){
    __shared__ float ov[512];
    __shared__ float red_s[8], red_q[8], mv[2];
    int t = threadIdx.x;
    ov[t] = o2[t];
    __syncthreads();
    const float* w = wproj + (size_t)t * 512;
    float acc = h1[t] + bproj[t];
    for (int k = 0; k < 512; k++) acc += ov[k] * w[k];
    float s = acc, q = acc * acc;
    for (int o = 32; o > 0; o >>= 1) { s += __shfl_down(s, o); q += __shfl_down(q, o); }
    if ((t & 63) == 0) { red_s[t >> 6] = s; red_q[t >> 6] = q; }
    __syncthreads();
    if (t == 0) {
        float S = 0.f, Q = 0.f;
        for (int i = 0; i < 8; i++) { S += red_s[i]; Q += red_q[i]; }
        float m = S / 512.0f;
        float v = Q / 512.0f - m * m;
        mv[0] = m; mv[1] = rsqrtf(v + EPS_LN);
    }
    __syncthreads();
    out[t] = (acc - mv[0]) * mv[1] * fcg[t];
}

extern "C" void kernel_launch(void* const* d_in, const int* in_sizes, int n_in,
                              void* d_out, int out_size, void* d_ws, size_t ws_size,
                              hipStream_t stream){
    const float* x      = (const float*)d_in[0];
    const float* cls    = (const float*)d_in[1];
    const float* ln_g1  = (const float*)d_in[2];
    const float* wqkv1  = (const float*)d_in[3];
    const float* wproj1 = (const float*)d_in[4];
    const float* bproj1 = (const float*)d_in[5];
    const float* resk1  = (const float*)d_in[6];
    const float* ln_g2  = (const float*)d_in[7];
    const float* wqkv2  = (const float*)d_in[8];
    const float* wproj2 = (const float*)d_in[9];
    const float* bproj2 = (const float*)d_in[10];
    const float* resk2  = (const float*)d_in[11];
    const float* fc_g   = (const float*)d_in[12];
    float* out = (float*)d_out;
    float* ws  = (float*)d_ws;

    float* h0   = ws;                          // NTOK*512
    float* ln   = h0  + (size_t)NTOK * 512;    // NTOK*512 (ln1; later small scratch)
    float* qkv  = ln  + (size_t)NTOK * 512;    // NTOK*1536 (qkv1; later kv2)
    float* attn = qkv + (size_t)NTOK * 1536;   // NTOK*512
    float* h1   = attn + (size_t)NTOK * 512;   // NTOK*512
    // layer-2 aliases (qkv1/ln1/h0 dead by the time these are written)
    float* ln2  = h0;
    float* kv2  = qkv;            // NTOK*1024
    float* q2   = ln;             // 512
    float* o2   = ln + 512;       // 512
    float* Lrow = ln + 1024;      // 8
    float* srow = ln + 2048;      // 8*NTOK

    // ---- layer 1 (full) ----
    concat_kernel<<<8194, 256, 0, stream>>>(x, cls, h0, NTOK * CDIM);
    ln_kernel<<<NTOK, 256, 0, stream>>>(h0, ln_g1, ln);
    gemm_abt<<<dim3(65, 24), 256, 0, stream>>>(ln, wqkv1, nullptr, nullptr, qkv, NTOK, 1536);
    flash1<<<dim3(129, 8), 256, 0, stream>>>(qkv, attn);
    convres_kernel<<<8194, 256, 0, stream>>>(qkv, resk1, attn);
    gemm_abt<<<dim3(65, 8), 256, 0, stream>>>(attn, wproj1, h0, bproj1, h1, NTOK, 512);

    // ---- layer 2 (only what token 0 needs) ----
    ln_kernel<<<NTOK, 256, 0, stream>>>(h1, ln_g2, ln2);
    gemm_abt<<<dim3(65, 16), 256, 0, stream>>>(ln2, wqkv2 + (size_t)512 * 512, nullptr, nullptr, kv2, NTOK, 1024);
    qrow_kernel<<<512, 64, 0, stream>>>(ln2, wqkv2, q2);
    srow_kernel<<<dim3(17, 8), 256, 0, stream>>>(q2, kv2, srow);
    softmax_row<<<8, 256, 0, stream>>>(srow, Lrow);
    pv_row<<<512, 256, 0, stream>>>(srow, kv2, Lrow, o2);
    conv0_kernel<<<1, 512, 0, stream>>>(kv2, resk2, o2);
    final_kernel<<<1, 512, 0, stream>>>(h1, o2, wproj2, bproj2, fc_g, out);
}

// Round 4
// 634.523 us; speedup vs baseline: 3.5337x; 3.5337x over previous
//
#include <hip/hip_runtime.h>
#include <math.h>

#define NTOK 4097
#define CDIM 512
#define EPS_LN 1e-5f

typedef float f32x4 __attribute__((ext_vector_type(4)));
typedef __bf16 bf16x8 __attribute__((ext_vector_type(8)));

__device__ inline unsigned short f2bf(float f){
    union { float f; unsigned u; } c; c.f = f;
    unsigned u = c.u;
    unsigned r = (u + 0x7fffu + ((u >> 16) & 1u)) >> 16;
    return (unsigned short)r;
}
__device__ inline unsigned cvt_pk_bf16(float lo, float hi){
    unsigned r;
    asm("v_cvt_pk_bf16_f32 %0, %1, %2" : "=v"(r) : "v"(lo), "v"(hi));
    return r;
}

// ---------------- concat: h0 = [cls; x] ----------------
__global__ void concat_kernel(const float* __restrict__ x, const float* __restrict__ cls,
                              float* __restrict__ h0, int total){
    int idx = blockIdx.x * 256 + threadIdx.x;
    if (idx >= total) return;
    int n = idx >> 9;
    int c = idx & 511;
    h0[idx] = (n == 0) ? cls[c] : x[(size_t)(n - 1) * CDIM + c];
}

// ---------------- layernorm (no bias), per token row of 512 ----------------
__global__ __launch_bounds__(256) void ln_kernel(const float* __restrict__ in,
                                                 const float* __restrict__ g,
                                                 float* __restrict__ out){
    int n = blockIdx.x;
    const float* row = in + (size_t)n * CDIM;
    int t = threadIdx.x;
    float x0 = row[t], x1 = row[t + 256];
    float s = x0 + x1, q = x0 * x0 + x1 * x1;
    for (int o = 32; o > 0; o >>= 1) { s += __shfl_down(s, o); q += __shfl_down(q, o); }
    __shared__ float rs[4], rq[4], mv[2];
    int wid = t >> 6;
    if ((t & 63) == 0) { rs[wid] = s; rq[wid] = q; }
    __syncthreads();
    if (t == 0) {
        float S = rs[0] + rs[1] + rs[2] + rs[3];
        float Q = rq[0] + rq[1] + rq[2] + rq[3];
        float m = S / 512.0f;
        float v = Q / 512.0f - m * m;
        mv[0] = m; mv[1] = rsqrtf(v + EPS_LN);
    }
    __syncthreads();
    float m = mv[0], r = mv[1];
    float* orow = out + (size_t)n * CDIM;
    orow[t]       = (x0 - m) * r * g[t];
    orow[t + 256] = (x1 - m) * r * g[t + 256];
}

// ---------------- generic fp32 GEMM: C[M,N] = A[M,512] * B[N,512]^T (+bias)(+resid) ----------------
__global__ __launch_bounds__(256) void gemm_abt(const float* __restrict__ A,
                                                const float* __restrict__ B,
                                                const float* __restrict__ resid,
                                                const float* __restrict__ bias,
                                                float* __restrict__ C, int M, int N){
    __shared__ float As[16][68];
    __shared__ float Bs[16][68];
    int t = threadIdx.x;
    int tx = t & 15, ty = t >> 4;
    int bm = blockIdx.x, bn = blockIdx.y;
    float acc[4][4] = {};
    int rl = t >> 2;
    int c4 = t & 3;
    int arow = bm * 64 + rl;
    int brow = bn * 64 + rl;
    for (int k0 = 0; k0 < 512; k0 += 16) {
        __syncthreads();
        float4 a4 = make_float4(0.f, 0.f, 0.f, 0.f);
        float4 b4 = make_float4(0.f, 0.f, 0.f, 0.f);
        if (arow < M) a4 = *(const float4*)(A + (size_t)arow * 512 + k0 + c4 * 4);
        if (brow < N) b4 = *(const float4*)(B + (size_t)brow * 512 + k0 + c4 * 4);
        As[c4 * 4 + 0][rl] = a4.x; As[c4 * 4 + 1][rl] = a4.y;
        As[c4 * 4 + 2][rl] = a4.z; As[c4 * 4 + 3][rl] = a4.w;
        Bs[c4 * 4 + 0][rl] = b4.x; Bs[c4 * 4 + 1][rl] = b4.y;
        Bs[c4 * 4 + 2][rl] = b4.z; Bs[c4 * 4 + 3][rl] = b4.w;
        __syncthreads();
        #pragma unroll
        for (int kk = 0; kk < 16; kk++) {
            float4 av = *(const float4*)(&As[kk][ty * 4]);
            float4 bv = *(const float4*)(&Bs[kk][tx * 4]);
            acc[0][0] += av.x * bv.x; acc[0][1] += av.x * bv.y; acc[0][2] += av.x * bv.z; acc[0][3] += av.x * bv.w;
            acc[1][0] += av.y * bv.x; acc[1][1] += av.y * bv.y; acc[1][2] += av.y * bv.z; acc[1][3] += av.y * bv.w;
            acc[2][0] += av.z * bv.x; acc[2][1] += av.z * bv.y; acc[2][2] += av.z * bv.z; acc[2][3] += av.z * bv.w;
            acc[3][0] += av.w * bv.x; acc[3][1] += av.w * bv.y; acc[3][2] += av.w * bv.z; acc[3][3] += av.w * bv.w;
        }
    }
    int row0 = bm * 64 + ty * 4;
    int col0 = bn * 64 + tx * 4;
    for (int i = 0; i < 4; i++) {
        int row = row0 + i;
        if (row >= M) continue;
        float* crow = C + (size_t)row * N;
        const float* rrow = resid ? (resid + (size_t)row * N) : nullptr;
        for (int j = 0; j < 4; j++) {
            int col = col0 + j;
            if (col >= N) continue;
            float v = acc[i][j];
            if (bias) v += bias[col];
            if (rrow) v += rrow[col];
            crow[col] = v;
        }
    }
}

// ---------------- layer-1 flash attention, bf16 MFMA ----------------
// Per block: head h, 64 query rows. 4 waves x 16 queries each.
// S^T = K*Q^T via mfma(A=K-frag, B=Q-frag)  -> C: col=lane&15=q, row=(lane>>4)*4+reg=key_local
// O^T = V^T*P^T via mfma(A=Vt-frag, B=P-frag) -> C: col=q, row=d_local
// Q/K/Vt tiles in LDS, bf16, XOR-swizzled: byte ^= (row&7)<<4
__global__ __launch_bounds__(256) void flash1_mfma(const float* __restrict__ qkv, float* __restrict__ out){
    __shared__ __align__(16) char smem[24576];
    unsigned short* Qs = (unsigned short*)smem;          // [64 q][64 d]
    unsigned short* Ks = Qs + 4096;                      // [64 key][64 d]
    unsigned short* Vt = Ks + 4096;                      // [64 d][64 key]
    const int h = blockIdx.y, qb = blockIdx.x;
    const int t = threadIdx.x;
    const int wave = t >> 6, lane = t & 63;
    const int g = lane >> 4, q = lane & 15;

    // ---- stage Q (pre-scaled by 0.125) ----
    {
        int rr = t >> 4;                 // 0..15
        int dc = (t & 15) * 4;           // d col base
        #pragma unroll
        for (int pp = 0; pp < 4; pp++) {
            int r = rr + pp * 16;
            int tok = qb * 64 + r;
            float4 v = make_float4(0.f, 0.f, 0.f, 0.f);
            if (tok < NTOK) v = *(const float4*)(qkv + (size_t)tok * 1536 + h * 64 + dc);
            ushort4 s;
            s.x = f2bf(v.x * 0.125f); s.y = f2bf(v.y * 0.125f);
            s.z = f2bf(v.z * 0.125f); s.w = f2bf(v.w * 0.125f);
            *(ushort4*)((char*)Qs + ((r * 128 + dc * 2) ^ ((r & 7) << 4))) = s;
        }
    }

    f32x4 acco[4] = {};                  // O^T accum: d = mt*16 + g*4 + reg, col = q
    float m_run = -INFINITY, l_run = 0.f;

    for (int kt = 0; kt < 65; kt++) {
        __syncthreads();                 // prev tile fully consumed
        // ---- stage K (row-major) and V (transposed scatter) ----
        {
            int rr = t >> 4, dc = (t & 15) * 4;
            #pragma unroll
            for (int pp = 0; pp < 4; pp++) {
                int r = rr + pp * 16;
                int tok = kt * 64 + r;
                float4 kv = make_float4(0.f, 0.f, 0.f, 0.f);
                float4 vv = make_float4(0.f, 0.f, 0.f, 0.f);
                if (tok < NTOK) {
                    const float* base = qkv + (size_t)tok * 1536 + 512 + h * 64 + dc;
                    kv = *(const float4*)(base);
                    vv = *(const float4*)(base + 512);
                }
                ushort4 s;
                s.x = f2bf(kv.x); s.y = f2bf(kv.y); s.z = f2bf(kv.z); s.w = f2bf(kv.w);
                *(ushort4*)((char*)Ks + ((r * 128 + dc * 2) ^ ((r & 7) << 4))) = s;
                unsigned short vs0 = f2bf(vv.x), vs1 = f2bf(vv.y), vs2 = f2bf(vv.z), vs3 = f2bf(vv.w);
                *(unsigned short*)((char*)Vt + (((dc + 0) * 128 + r * 2) ^ (((dc + 0) & 7) << 4))) = vs0;
                *(unsigned short*)((char*)Vt + (((dc + 1) * 128 + r * 2) ^ (((dc + 1) & 7) << 4))) = vs1;
                *(unsigned short*)((char*)Vt + (((dc + 2) * 128 + r * 2) ^ (((dc + 2) & 7) << 4))) = vs2;
                *(unsigned short*)((char*)Vt + (((dc + 3) * 128 + r * 2) ^ (((dc + 3) & 7) << 4))) = vs3;
            }
        }
        __syncthreads();

        // ---- S^T = K * Q^T ----
        f32x4 accs[4] = {};
        #pragma unroll
        for (int ks = 0; ks < 2; ks++) {
            int qrow = wave * 16 + q;
            bf16x8 bq = *(const bf16x8*)((char*)Qs + ((qrow * 128 + ks * 64 + g * 16) ^ ((qrow & 7) << 4)));
            #pragma unroll
            for (int mt = 0; mt < 4; mt++) {
                int kr = mt * 16 + q;
                bf16x8 ak = *(const bf16x8*)((char*)Ks + ((kr * 128 + ks * 64 + g * 16) ^ ((kr & 7) << 4)));
                accs[mt] = __builtin_amdgcn_mfma_f32_16x16x32_bf16(ak, bq, accs[mt], 0, 0, 0);
            }
        }

        // ---- online softmax (per q = lane&15; keys lane-local + xor16/32) ----
        float pr[4][4];
        float tmax = -INFINITY;
        #pragma unroll
        for (int mt = 0; mt < 4; mt++)
            #pragma unroll
            for (int rg = 0; rg < 4; rg++) {
                float s = accs[mt][rg];
                if (kt == 64 && (4096 + mt * 16 + g * 4 + rg) >= NTOK) s = -INFINITY;
                pr[mt][rg] = s;
                tmax = fmaxf(tmax, s);
            }
        tmax = fmaxf(tmax, __shfl_xor(tmax, 16));
        tmax = fmaxf(tmax, __shfl_xor(tmax, 32));
        float mn = fmaxf(m_run, tmax);
        float alpha = __expf(m_run - mn);
        float psum = 0.f;
        #pragma unroll
        for (int mt = 0; mt < 4; mt++)
            #pragma unroll
            for (int rg = 0; rg < 4; rg++) {
                float pv = __expf(pr[mt][rg] - mn);
                pr[mt][rg] = pv;
                psum += pv;
            }
        psum += __shfl_xor(psum, 16);
        psum += __shfl_xor(psum, 32);
        l_run = l_run * alpha + psum;
        m_run = mn;
        #pragma unroll
        for (int mt = 0; mt < 4; mt++)
            #pragma unroll
            for (int rg = 0; rg < 4; rg++)
                acco[mt][rg] *= alpha;

        // ---- pack P to bf16 pairs ----
        unsigned pk[4][2];
        #pragma unroll
        for (int mt = 0; mt < 4; mt++) {
            pk[mt][0] = cvt_pk_bf16(pr[mt][0], pr[mt][1]);
            pk[mt][1] = cvt_pk_bf16(pr[mt][2], pr[mt][3]);
        }

        // ---- O^T += V^T * P^T ----
        #pragma unroll
        for (int ks = 0; ks < 2; ks++) {
            union { unsigned w[4]; bf16x8 v; } bp;
            #pragma unroll
            for (int sh = 0; sh < 2; sh++)
                #pragma unroll
                for (int rp = 0; rp < 2; rp++) {
                    int src = ((g & 1) * 2 + sh) * 16 + q;
                    unsigned r0 = __shfl(pk[2 * ks + 0][rp], src);
                    unsigned r1 = __shfl(pk[2 * ks + 1][rp], src);
                    bp.w[sh * 2 + rp] = (g < 2) ? r0 : r1;
                }
            #pragma unroll
            for (int mt = 0; mt < 4; mt++) {
                int dr = mt * 16 + q;
                bf16x8 av = *(const bf16x8*)((char*)Vt + ((dr * 128 + ks * 64 + g * 16) ^ ((dr & 7) << 4)));
                acco[mt] = __builtin_amdgcn_mfma_f32_16x16x32_bf16(av, bp.v, acco[mt], 0, 0, 0);
            }
        }
    }

    // ---- epilogue: O^T -> LDS transpose -> coalesced f32 stores ----
    float inv = 1.0f / l_run;
    __syncthreads();                     // done with Q/K/Vt LDS
    float* ob = (float*)smem + wave * 16 * 68;   // [16 q][68]
    #pragma unroll
    for (int mt = 0; mt < 4; mt++)
        #pragma unroll
        for (int rg = 0; rg < 4; rg++)
            ob[q * 68 + mt * 16 + g * 4 + rg] = acco[mt][rg] * inv;
    __syncthreads();
    {
        int ql = lane >> 2;
        int tok = qb * 64 + wave * 16 + ql;
        #pragma unroll
        for (int i = 0; i < 4; i++) {
            int c = (lane & 3) + i * 4;
            if (tok < NTOK)
                *(float4*)(out + (size_t)tok * 512 + h * 64 + c * 4) = *(const float4*)(ob + ql * 68 + c * 4);
        }
    }
}

// ---------------- layer-1 depthwise conv residual add (into attn buffer) ----------------
__global__ void convres_kernel(const float* __restrict__ qkv, const float* __restrict__ rk,
                               float* __restrict__ attn){
    int idx = blockIdx.x * 256 + threadIdx.x;
    if (idx >= NTOK * CDIM) return;
    int n = idx >> 9, hd = idx & 511, h = hd >> 6;
    float a = attn[idx];
    const float* kr = rk + h * 33;
    #pragma unroll
    for (int k = 0; k < 33; k++) {
        int mm = n + k - 16;
        if (mm >= 0 && mm < NTOK)
            a += qkv[(size_t)mm * 1536 + 1024 + hd] * kr[k];
    }
    attn[idx] = a;
}

// ---------------- layer 2: q row 0 ----------------
__global__ void qrow_kernel(const float* __restrict__ ln2, const float* __restrict__ wqkv,
                            float* __restrict__ q2){
    int j = blockIdx.x;
    int lane = threadIdx.x;
    const float* w = wqkv + (size_t)j * 512;
    float s = 0.f;
    for (int k = lane; k < 512; k += 64) s += ln2[k] * w[k];
    for (int o = 32; o > 0; o >>= 1) s += __shfl_down(s, o);
    if (lane == 0) q2[j] = s;
}

// ---------------- layer 2: score row 0 (all heads) ----------------
__global__ void srow_kernel(const float* __restrict__ q2, const float* __restrict__ kv2,
                            float* __restrict__ srow){
    int mm = blockIdx.x * 256 + threadIdx.x;
    int h = blockIdx.y;
    if (mm >= NTOK) return;
    const float* q = q2 + h * 64;
    const float* k = kv2 + (size_t)mm * 1024 + h * 64;
    float s = 0.f;
    #pragma unroll
    for (int d = 0; d < 64; d++) s += q[d] * k[d];
    srow[(size_t)h * NTOK + mm] = s * 0.125f;
}

// ---------------- layer 2: softmax over score row ----------------
__global__ __launch_bounds__(256) void softmax_row(float* __restrict__ srow, float* __restrict__ Lout){
    int h = blockIdx.x, t = threadIdx.x;
    float* s = srow + (size_t)h * NTOK;
    __shared__ float red[4];
    float mx = -INFINITY;
    for (int i = t; i < NTOK; i += 256) mx = fmaxf(mx, s[i]);
    for (int o = 32; o > 0; o >>= 1) mx = fmaxf(mx, __shfl_xor(mx, o));
    if ((t & 63) == 0) red[t >> 6] = mx;
    __syncthreads();
    mx = fmaxf(fmaxf(red[0], red[1]), fmaxf(red[2], red[3]));
    __syncthreads();
    float sum = 0.f;
    for (int i = t; i < NTOK; i += 256) { float p = __expf(s[i] - mx); s[i] = p; sum += p; }
    for (int o = 32; o > 0; o >>= 1) sum += __shfl_xor(sum, o);
    if ((t & 63) == 0) red[t >> 6] = sum;
    __syncthreads();
    if (t == 0) Lout[h] = red[0] + red[1] + red[2] + red[3];
}

// ---------------- layer 2: o2[hd] = sum_m p[h][m] * v2[m][hd] / L[h] ----------------
__global__ __launch_bounds__(256) void pv_row(const float* __restrict__ srow, const float* __restrict__ kv2,
                                              const float* __restrict__ L, float* __restrict__ o2){
    int hd = blockIdx.x;
    int h = hd >> 6;
    int t = threadIdx.x;
    const float* p = srow + (size_t)h * NTOK;
    const float* v = kv2 + 512 + hd;
    float s = 0.f;
    for (int i = t; i < NTOK; i += 256) s += p[i] * v[(size_t)i * 1024];
    for (int o = 32; o > 0; o >>= 1) s += __shfl_down(s, o);
    __shared__ float red[4];
    if ((t & 63) == 0) red[t >> 6] = s;
    __syncthreads();
    if (t == 0) o2[hd] = (red[0] + red[1] + red[2] + red[3]) / L[h];
}

// ---------------- layer 2: conv at position 0, add into o2 ----------------
__global__ void conv0_kernel(const float* __restrict__ kv2, const float* __restrict__ rk,
                             float* __restrict__ o2){
    int hd = threadIdx.x;
    int h = hd >> 6;
    float a = o2[hd];
    #pragma unroll
    for (int k = 16; k < 33; k++)
        a += kv2[(size_t)(k - 16) * 1024 + 512 + hd] * rk[h * 33 + k];
    o2[hd] = a;
}

// ---------------- final: proj row 0 + residual + layernorm ----------------
__global__ __launch_bounds__(512) void final_kernel(const float* __restrict__ h1, const float* __restrict__ o2,
                                                    const float* __restrict__ wproj, const float* __restrict__ bproj,
                                                    const float* __restrict__ fcg, float* __restrict__ out){
    __shared__ float ov[512];
    __shared__ float red_s[8], red_q[8], mv[2];
    int t = threadIdx.x;
    ov[t] = o2[t];
    __syncthreads();
    const float* w = wproj + (size_t)t * 512;
    float acc = h1[t] + bproj[t];
    for (int k = 0; k < 512; k++) acc += ov[k] * w[k];
    float s = acc, q = acc * acc;
    for (int o = 32; o > 0; o >>= 1) { s += __shfl_down(s, o); q += __shfl_down(q, o); }
    if ((t & 63) == 0) { red_s[t >> 6] = s; red_q[t >> 6] = q; }
    __syncthreads();
    if (t == 0) {
        float S = 0.f, Q = 0.f;
        for (int i = 0; i < 8; i++) { S += red_s[i]; Q += red_q[i]; }
        float m = S / 512.0f;
        float v = Q / 512.0f - m * m;
        mv[0] = m; mv[1] = rsqrtf(v + EPS_LN);
    }
    __syncthreads();
    out[t] = (acc - mv[0]) * mv[1] * fcg[t];
}

extern "C" void kernel_launch(void* const* d_in, const int* in_sizes, int n_in,
                              void* d_out, int out_size, void* d_ws, size_t ws_size,
                              hipStream_t stream){
    const float* x      = (const float*)d_in[0];
    const float* cls    = (const float*)d_in[1];
    const float* ln_g1  = (const float*)d_in[2];
    const float* wqkv1  = (const float*)d_in[3];
    const float* wproj1 = (const float*)d_in[4];
    const float* bproj1 = (const float*)d_in[5];
    const float* resk1  = (const float*)d_in[6];
    const float* ln_g2  = (const float*)d_in[7];
    const float* wqkv2  = (const float*)d_in[8];
    const float* wproj2 = (const float*)d_in[9];
    const float* bproj2 = (const float*)d_in[10];
    const float* resk2  = (const float*)d_in[11];
    const float* fc_g   = (const float*)d_in[12];
    float* out = (float*)d_out;
    float* ws  = (float*)d_ws;

    float* h0   = ws;                          // NTOK*512
    float* ln   = h0  + (size_t)NTOK * 512;    // NTOK*512
    float* qkv  = ln  + (size_t)NTOK * 512;    // NTOK*1536
    float* attn = qkv + (size_t)NTOK * 1536;   // NTOK*512
    float* h1   = attn + (size_t)NTOK * 512;   // NTOK*512
    float* ln2  = h0;
    float* kv2  = qkv;            // NTOK*1024
    float* q2   = ln;             // 512
    float* o2   = ln + 512;       // 512
    float* Lrow = ln + 1024;      // 8
    float* srow = ln + 2048;      // 8*NTOK

    // ---- layer 1 (full) ----
    concat_kernel<<<8194, 256, 0, stream>>>(x, cls, h0, NTOK * CDIM);
    ln_kernel<<<NTOK, 256, 0, stream>>>(h0, ln_g1, ln);
    gemm_abt<<<dim3(65, 24), 256, 0, stream>>>(ln, wqkv1, nullptr, nullptr, qkv, NTOK, 1536);
    flash1_mfma<<<dim3(65, 8), 256, 0, stream>>>(qkv, attn);
    convres_kernel<<<8194, 256, 0, stream>>>(qkv, resk1, attn);
    gemm_abt<<<dim3(65, 8), 256, 0, stream>>>(attn, wproj1, h0, bproj1, h1, NTOK, 512);

    // ---- layer 2 (only what token 0 needs) ----
    ln_kernel<<<NTOK, 256, 0, stream>>>(h1, ln_g2, ln2);
    gemm_abt<<<dim3(65, 16), 256, 0, stream>>>(ln2, wqkv2 + (size_t)512 * 512, nullptr, nullptr, kv2, NTOK, 1024);
    qrow_kernel<<<512, 64, 0, stream>>>(ln2, wqkv2, q2);
    srow_kernel<<<dim3(17, 8), 256, 0, stream>>>(q2, kv2, srow);
    softmax_row<<<8, 256, 0, stream>>>(srow, Lrow);
    pv_row<<<512, 256, 0, stream>>>(srow, kv2, Lrow, o2);
    conv0_kernel<<<1, 512, 0, stream>>>(kv2, resk2, o2);
    final_kernel<<<1, 512, 0, stream>>>(h1, o2, wproj2, bproj2, fc_g, out);
}

// Round 5
// 485.636 us; speedup vs baseline: 4.6171x; 1.3066x over previous
//
#include <hip/hip_runtime.h>
#include <math.h>

#define NTOK 4097
#define CDIM 512
#define EPS_LN 1e-5f

typedef float f32x4 __attribute__((ext_vector_type(4)));
typedef __bf16 bf16x8 __attribute__((ext_vector_type(8)));

__device__ inline unsigned short f2bf(float f){
    union { float f; unsigned u; } c; c.f = f;
    unsigned u = c.u;
    unsigned r = (u + 0x7fffu + ((u >> 16) & 1u)) >> 16;
    return (unsigned short)r;
}
__device__ inline float bf2f(unsigned short b){
    union { unsigned u; float f; } c; c.u = ((unsigned)b) << 16;
    return c.f;
}
__device__ inline unsigned cvt_pk_bf16(float lo, float hi){
    unsigned r;
    asm("v_cvt_pk_bf16_f32 %0, %1, %2" : "=v"(r) : "v"(lo), "v"(hi));
    return r;
}

// ---------------- concat: h0 = [cls; x] ----------------
__global__ void concat_kernel(const float* __restrict__ x, const float* __restrict__ cls,
                              float* __restrict__ h0, int total){
    int idx = blockIdx.x * 256 + threadIdx.x;
    if (idx >= total) return;
    int n = idx >> 9;
    int c = idx & 511;
    h0[idx] = (n == 0) ? cls[c] : x[(size_t)(n - 1) * CDIM + c];
}

// ---------------- cast f32 -> bf16 (n multiple of 4) ----------------
__global__ void cast_bf_kernel(const float* __restrict__ src, unsigned short* __restrict__ dst, int n){
    int i = (blockIdx.x * 256 + threadIdx.x) * 4;
    if (i >= n) return;
    float4 v = *(const float4*)(src + i);
    ushort4 o;
    o.x = f2bf(v.x); o.y = f2bf(v.y); o.z = f2bf(v.z); o.w = f2bf(v.w);
    *(ushort4*)(dst + i) = o;
}

// ---------------- layernorm (no bias) -> bf16 out ----------------
__global__ __launch_bounds__(256) void ln_kernel(const float* __restrict__ in,
                                                 const float* __restrict__ g,
                                                 unsigned short* __restrict__ out){
    int n = blockIdx.x;
    const float* row = in + (size_t)n * CDIM;
    int t = threadIdx.x;
    float x0 = row[t], x1 = row[t + 256];
    float s = x0 + x1, q = x0 * x0 + x1 * x1;
    for (int o = 32; o > 0; o >>= 1) { s += __shfl_down(s, o); q += __shfl_down(q, o); }
    __shared__ float rs[4], rq[4], mv[2];
    int wid = t >> 6;
    if ((t & 63) == 0) { rs[wid] = s; rq[wid] = q; }
    __syncthreads();
    if (t == 0) {
        float S = rs[0] + rs[1] + rs[2] + rs[3];
        float Q = rq[0] + rq[1] + rq[2] + rq[3];
        float m = S / 512.0f;
        float v = Q / 512.0f - m * m;
        mv[0] = m; mv[1] = rsqrtf(v + EPS_LN);
    }
    __syncthreads();
    float m = mv[0], r = mv[1];
    unsigned short* orow = out + (size_t)n * CDIM;
    orow[t]       = f2bf((x0 - m) * r * g[t]);
    orow[t + 256] = f2bf((x1 - m) * r * g[t + 256]);
}

// ---------------- bf16 MFMA GEMM: C[M,N] = A[M,512] * B[N,512]^T (+bias)(+resid), fp32 out ----
// 128x128 tile, BK=64, 4 waves (2x2), each wave 64x64 via 4x4 frags of 16x16x32.
__global__ __launch_bounds__(256) void gemm_bf16(const unsigned short* __restrict__ A,
                                                 const unsigned short* __restrict__ B,
                                                 const float* __restrict__ resid,
                                                 const float* __restrict__ bias,
                                                 float* __restrict__ C, int M, int N){
    __shared__ unsigned short As[128][72];   // +8 pad: row stride 144B -> 2-way conflicts only
    __shared__ unsigned short Bs[128][72];
    int t = threadIdx.x;
    int wave = t >> 6, lane = t & 63;
    int wr = wave >> 1, wc = wave & 1;
    int bm = blockIdx.x, bn = blockIdx.y;
    f32x4 acc[4][4] = {};
    int lrow = t >> 3;
    int lc8 = (t & 7) * 8;
    for (int k0 = 0; k0 < 512; k0 += 64) {
        __syncthreads();
        #pragma unroll
        for (int i = 0; i < 4; i++) {
            int row = lrow + i * 32;
            int ar = bm * 128 + row; if (ar > M - 1) ar = M - 1;
            int br = bn * 128 + row;              // N is a multiple of 128
            *(uint4*)(&As[row][lc8]) = *(const uint4*)(A + (size_t)ar * 512 + k0 + lc8);
            *(uint4*)(&Bs[row][lc8]) = *(const uint4*)(B + (size_t)br * 512 + k0 + lc8);
        }
        __syncthreads();
        #pragma unroll
        for (int ks = 0; ks < 2; ks++) {
            bf16x8 af[4], bfr[4];
            #pragma unroll
            for (int mi = 0; mi < 4; mi++)
                af[mi] = *(const bf16x8*)(&As[wr * 64 + mi * 16 + (lane & 15)][ks * 32 + (lane >> 4) * 8]);
            #pragma unroll
            for (int ni = 0; ni < 4; ni++)
                bfr[ni] = *(const bf16x8*)(&Bs[wc * 64 + ni * 16 + (lane & 15)][ks * 32 + (lane >> 4) * 8]);
            #pragma unroll
            for (int mi = 0; mi < 4; mi++)
                #pragma unroll
                for (int ni = 0; ni < 4; ni++)
                    acc[mi][ni] = __builtin_amdgcn_mfma_f32_16x16x32_bf16(af[mi], bfr[ni], acc[mi][ni], 0, 0, 0);
        }
    }
    int n0 = bn * 128 + wc * 64;
    #pragma unroll
    for (int mi = 0; mi < 4; mi++) {
        #pragma unroll
        for (int rg = 0; rg < 4; rg++) {
            int m = bm * 128 + wr * 64 + mi * 16 + (lane >> 4) * 4 + rg;
            if (m < M) {
                float* crow = C + (size_t)m * N;
                const float* rrow = resid ? resid + (size_t)m * N : nullptr;
                #pragma unroll
                for (int ni = 0; ni < 4; ni++) {
                    int n = n0 + ni * 16 + (lane & 15);
                    float v = acc[mi][ni][rg];
                    if (bias) v += bias[n];
                    if (rrow) v += rrow[n];
                    crow[n] = v;
                }
            }
        }
    }
}

// ---------------- layer-1 flash attention, bf16 MFMA ----------------
__global__ __launch_bounds__(256) void flash1_mfma(const float* __restrict__ qkv, float* __restrict__ out){
    __shared__ __align__(16) char smem[24576];
    unsigned short* Qs = (unsigned short*)smem;          // [64 q][64 d]
    unsigned short* Ks = Qs + 4096;                      // [64 key][64 d]
    unsigned short* Vt = Ks + 4096;                      // [64 d][64 key]
    const int h = blockIdx.y, qb = blockIdx.x;
    const int t = threadIdx.x;
    const int wave = t >> 6, lane = t & 63;
    const int g = lane >> 4, q = lane & 15;

    {
        int rr = t >> 4;
        int dc = (t & 15) * 4;
        #pragma unroll
        for (int pp = 0; pp < 4; pp++) {
            int r = rr + pp * 16;
            int tok = qb * 64 + r;
            float4 v = make_float4(0.f, 0.f, 0.f, 0.f);
            if (tok < NTOK) v = *(const float4*)(qkv + (size_t)tok * 1536 + h * 64 + dc);
            ushort4 s;
            s.x = f2bf(v.x * 0.125f); s.y = f2bf(v.y * 0.125f);
            s.z = f2bf(v.z * 0.125f); s.w = f2bf(v.w * 0.125f);
            *(ushort4*)((char*)Qs + ((r * 128 + dc * 2) ^ ((r & 7) << 4))) = s;
        }
    }

    f32x4 acco[4] = {};
    float m_run = -INFINITY, l_run = 0.f;

    for (int kt = 0; kt < 65; kt++) {
        __syncthreads();
        {
            int rr = t >> 4, dc = (t & 15) * 4;
            #pragma unroll
            for (int pp = 0; pp < 4; pp++) {
                int r = rr + pp * 16;
                int tok = kt * 64 + r;
                float4 kv = make_float4(0.f, 0.f, 0.f, 0.f);
                float4 vv = make_float4(0.f, 0.f, 0.f, 0.f);
                if (tok < NTOK) {
                    const float* base = qkv + (size_t)tok * 1536 + 512 + h * 64 + dc;
                    kv = *(const float4*)(base);
                    vv = *(const float4*)(base + 512);
                }
                ushort4 s;
                s.x = f2bf(kv.x); s.y = f2bf(kv.y); s.z = f2bf(kv.z); s.w = f2bf(kv.w);
                *(ushort4*)((char*)Ks + ((r * 128 + dc * 2) ^ ((r & 7) << 4))) = s;
                unsigned short vs0 = f2bf(vv.x), vs1 = f2bf(vv.y), vs2 = f2bf(vv.z), vs3 = f2bf(vv.w);
                *(unsigned short*)((char*)Vt + (((dc + 0) * 128 + r * 2) ^ (((dc + 0) & 7) << 4))) = vs0;
                *(unsigned short*)((char*)Vt + (((dc + 1) * 128 + r * 2) ^ (((dc + 1) & 7) << 4))) = vs1;
                *(unsigned short*)((char*)Vt + (((dc + 2) * 128 + r * 2) ^ (((dc + 2) & 7) << 4))) = vs2;
                *(unsigned short*)((char*)Vt + (((dc + 3) * 128 + r * 2) ^ (((dc + 3) & 7) << 4))) = vs3;
            }
        }
        __syncthreads();

        f32x4 accs[4] = {};
        #pragma unroll
        for (int ks = 0; ks < 2; ks++) {
            int qrow = wave * 16 + q;
            bf16x8 bq = *(const bf16x8*)((char*)Qs + ((qrow * 128 + ks * 64 + g * 16) ^ ((qrow & 7) << 4)));
            #pragma unroll
            for (int mt = 0; mt < 4; mt++) {
                int kr = mt * 16 + q;
                bf16x8 ak = *(const bf16x8*)((char*)Ks + ((kr * 128 + ks * 64 + g * 16) ^ ((kr & 7) << 4)));
                accs[mt] = __builtin_amdgcn_mfma_f32_16x16x32_bf16(ak, bq, accs[mt], 0, 0, 0);
            }
        }

        float pr[4][4];
        float tmax = -INFINITY;
        #pragma unroll
        for (int mt = 0; mt < 4; mt++)
            #pragma unroll
            for (int rg = 0; rg < 4; rg++) {
                float s = accs[mt][rg];
                if (kt == 64 && (4096 + mt * 16 + g * 4 + rg) >= NTOK) s = -INFINITY;
                pr[mt][rg] = s;
                tmax = fmaxf(tmax, s);
            }
        tmax = fmaxf(tmax, __shfl_xor(tmax, 16));
        tmax = fmaxf(tmax, __shfl_xor(tmax, 32));
        float mn = fmaxf(m_run, tmax);
        float alpha = __expf(m_run - mn);
        float psum = 0.f;
        #pragma unroll
        for (int mt = 0; mt < 4; mt++)
            #pragma unroll
            for (int rg = 0; rg < 4; rg++) {
                float pv = __expf(pr[mt][rg] - mn);
                pr[mt][rg] = pv;
                psum += pv;
            }
        psum += __shfl_xor(psum, 16);
        psum += __shfl_xor(psum, 32);
        l_run = l_run * alpha + psum;
        m_run = mn;
        #pragma unroll
        for (int mt = 0; mt < 4; mt++)
            #pragma unroll
            for (int rg = 0; rg < 4; rg++)
                acco[mt][rg] *= alpha;

        unsigned pk[4][2];
        #pragma unroll
        for (int mt = 0; mt < 4; mt++) {
            pk[mt][0] = cvt_pk_bf16(pr[mt][0], pr[mt][1]);
            pk[mt][1] = cvt_pk_bf16(pr[mt][2], pr[mt][3]);
        }

        #pragma unroll
        for (int ks = 0; ks < 2; ks++) {
            union { unsigned w[4]; bf16x8 v; } bp;
            #pragma unroll
            for (int sh = 0; sh < 2; sh++)
                #pragma unroll
                for (int rp = 0; rp < 2; rp++) {
                    int src = ((g & 1) * 2 + sh) * 16 + q;
                    unsigned r0 = __shfl(pk[2 * ks + 0][rp], src);
                    unsigned r1 = __shfl(pk[2 * ks + 1][rp], src);
                    bp.w[sh * 2 + rp] = (g < 2) ? r0 : r1;
                }
            #pragma unroll
            for (int mt = 0; mt < 4; mt++) {
                int dr = mt * 16 + q;
                bf16x8 av = *(const bf16x8*)((char*)Vt + ((dr * 128 + ks * 64 + g * 16) ^ ((dr & 7) << 4)));
                acco[mt] = __builtin_amdgcn_mfma_f32_16x16x32_bf16(av, bp.v, acco[mt], 0, 0, 0);
            }
        }
    }

    float inv = 1.0f / l_run;
    __syncthreads();
    float* ob = (float*)smem + wave * 16 * 68;
    #pragma unroll
    for (int mt = 0; mt < 4; mt++)
        #pragma unroll
        for (int rg = 0; rg < 4; rg++)
            ob[q * 68 + mt * 16 + g * 4 + rg] = acco[mt][rg] * inv;
    __syncthreads();
    {
        int ql = lane >> 2;
        int tok = qb * 64 + wave * 16 + ql;
        #pragma unroll
        for (int i = 0; i < 4; i++) {
            int c = (lane & 3) + i * 4;
            if (tok < NTOK)
                *(float4*)(out + (size_t)tok * 512 + h * 64 + c * 4) = *(const float4*)(ob + ql * 68 + c * 4);
        }
    }
}

// ---------------- layer-1 depthwise conv residual add -> bf16 out ----------------
__global__ void convres_kernel(const float* __restrict__ qkv, const float* __restrict__ rk,
                               const float* __restrict__ attn, unsigned short* __restrict__ attn_bf){
    int idx = blockIdx.x * 256 + threadIdx.x;
    if (idx >= NTOK * CDIM) return;
    int n = idx >> 9, hd = idx & 511, h = hd >> 6;
    float a = attn[idx];
    const float* kr = rk + h * 33;
    #pragma unroll
    for (int k = 0; k < 33; k++) {
        int mm = n + k - 16;
        if (mm >= 0 && mm < NTOK)
            a += qkv[(size_t)mm * 1536 + 1024 + hd] * kr[k];
    }
    attn_bf[idx] = f2bf(a);
}

// ---------------- layer 2: q row 0 (ln2 in bf16) ----------------
__global__ void qrow_kernel(const unsigned short* __restrict__ ln2b, const float* __restrict__ wqkv,
                            float* __restrict__ q2){
    int j = blockIdx.x;
    int lane = threadIdx.x;
    const float* w = wqkv + (size_t)j * 512;
    float s = 0.f;
    for (int k = lane; k < 512; k += 64) s += bf2f(ln2b[k]) * w[k];
    for (int o = 32; o > 0; o >>= 1) s += __shfl_down(s, o);
    if (lane == 0) q2[j] = s;
}

// ---------------- layer 2: score row 0 ----------------
__global__ void srow_kernel(const float* __restrict__ q2, const float* __restrict__ kv2,
                            float* __restrict__ srow){
    int mm = blockIdx.x * 256 + threadIdx.x;
    int h = blockIdx.y;
    if (mm >= NTOK) return;
    const float* q = q2 + h * 64;
    const float* k = kv2 + (size_t)mm * 1024 + h * 64;
    float s = 0.f;
    #pragma unroll
    for (int d = 0; d < 64; d++) s += q[d] * k[d];
    srow[(size_t)h * NTOK + mm] = s * 0.125f;
}

// ---------------- layer 2: softmax over score row ----------------
__global__ __launch_bounds__(256) void softmax_row(float* __restrict__ srow, float* __restrict__ Lout){
    int h = blockIdx.x, t = threadIdx.x;
    float* s = srow + (size_t)h * NTOK;
    __shared__ float red[4];
    float mx = -INFINITY;
    for (int i = t; i < NTOK; i += 256) mx = fmaxf(mx, s[i]);
    for (int o = 32; o > 0; o >>= 1) mx = fmaxf(mx, __shfl_xor(mx, o));
    if ((t & 63) == 0) red[t >> 6] = mx;
    __syncthreads();
    mx = fmaxf(fmaxf(red[0], red[1]), fmaxf(red[2], red[3]));
    __syncthreads();
    float sum = 0.f;
    for (int i = t; i < NTOK; i += 256) { float p = __expf(s[i] - mx); s[i] = p; sum += p; }
    for (int o = 32; o > 0; o >>= 1) sum += __shfl_xor(sum, o);
    if ((t & 63) == 0) red[t >> 6] = sum;
    __syncthreads();
    if (t == 0) Lout[h] = red[0] + red[1] + red[2] + red[3];
}

// ---------------- layer 2: o2[hd] = sum_m p[h][m] * v2[m][hd] / L[h] ----------------
__global__ __launch_bounds__(256) void pv_row(const float* __restrict__ srow, const float* __restrict__ kv2,
                                              const float* __restrict__ L, float* __restrict__ o2){
    int hd = blockIdx.x;
    int h = hd >> 6;
    int t = threadIdx.x;
    const float* p = srow + (size_t)h * NTOK;
    const float* v = kv2 + 512 + hd;
    float s = 0.f;
    for (int i = t; i < NTOK; i += 256) s += p[i] * v[(size_t)i * 1024];
    for (int o = 32; o > 0; o >>= 1) s += __shfl_down(s, o);
    __shared__ float red[4];
    if ((t & 63) == 0) red[t >> 6] = s;
    __syncthreads();
    if (t == 0) o2[hd] = (red[0] + red[1] + red[2] + red[3]) / L[h];
}

// ---------------- layer 2: conv at position 0 ----------------
__global__ void conv0_kernel(const float* __restrict__ kv2, const float* __restrict__ rk,
                             float* __restrict__ o2){
    int hd = threadIdx.x;
    int h = hd >> 6;
    float a = o2[hd];
    #pragma unroll
    for (int k = 16; k < 33; k++)
        a += kv2[(size_t)(k - 16) * 1024 + 512 + hd] * rk[h * 33 + k];
    o2[hd] = a;
}

// ---------------- final: proj row 0 + residual + layernorm ----------------
__global__ __launch_bounds__(512) void final_kernel(const float* __restrict__ h1, const float* __restrict__ o2,
                                                    const float* __restrict__ wproj, const float* __restrict__ bproj,
                                                    const float* __restrict__ fcg, float* __restrict__ out){
    __shared__ float ov[512];
    __shared__ float red_s[8], red_q[8], mv[2];
    int t = threadIdx.x;
    ov[t] = o2[t];
    __syncthreads();
    const float* w = wproj + (size_t)t * 512;
    float acc = h1[t] + bproj[t];
    for (int k = 0; k < 512; k++) acc += ov[k] * w[k];
    float s = acc, q = acc * acc;
    for (int o = 32; o > 0; o >>= 1) { s += __shfl_down(s, o); q += __shfl_down(q, o); }
    if ((t & 63) == 0) { red_s[t >> 6] = s; red_q[t >> 6] = q; }
    __syncthreads();
    if (t == 0) {
        float S = 0.f, Q = 0.f;
        for (int i = 0; i < 8; i++) { S += red_s[i]; Q += red_q[i]; }
        float m = S / 512.0f;
        float v = Q / 512.0f - m * m;
        mv[0] = m; mv[1] = rsqrtf(v + EPS_LN);
    }
    __syncthreads();
    out[t] = (acc - mv[0]) * mv[1] * fcg[t];
}

extern "C" void kernel_launch(void* const* d_in, const int* in_sizes, int n_in,
                              void* d_out, int out_size, void* d_ws, size_t ws_size,
                              hipStream_t stream){
    const float* x      = (const float*)d_in[0];
    const float* cls    = (const float*)d_in[1];
    const float* ln_g1  = (const float*)d_in[2];
    const float* wqkv1  = (const float*)d_in[3];
    const float* wproj1 = (const float*)d_in[4];
    const float* bproj1 = (const float*)d_in[5];
    const float* resk1  = (const float*)d_in[6];
    const float* ln_g2  = (const float*)d_in[7];
    const float* wqkv2  = (const float*)d_in[8];
    const float* wproj2 = (const float*)d_in[9];
    const float* bproj2 = (const float*)d_in[10];
    const float* resk2  = (const float*)d_in[11];
    const float* fc_g   = (const float*)d_in[12];
    float* out = (float*)d_out;
    float* ws  = (float*)d_ws;

    const size_t NC = (size_t)NTOK * 512;          // 2,097,664
    float* h0   = ws;                              // NC f32
    float* qkv  = h0 + NC;                         // NTOK*1536 f32 (layer2: kv2 alias)
    float* attn = qkv + (size_t)NTOK * 1536;       // NC f32
    float* h1   = attn + NC;                       // NC f32
    float* sm   = h1 + NC;                         // small fp32 scratch
    float* q2   = sm;                              // 512
    float* o2   = sm + 512;                        // 512
    float* Lrow = sm + 1024;                       // 8
    float* srow = sm + 2048;                       // 8*NTOK = 32776
    unsigned short* bfbuf = (unsigned short*)(sm + 40960);  // NC bf16 (ln1 / attn_bf / ln2, sequential reuse)
    unsigned short* wq1b  = bfbuf + NC;            // 1536*512
    unsigned short* wp1b  = wq1b + 1536 * 512;     // 512*512
    unsigned short* wkv2b = wp1b + 512 * 512;      // 1024*512
    float* kv2 = qkv;

    // ---- one-time weight casts (independent) ----
    cast_bf_kernel<<<768, 256, 0, stream>>>(wqkv1, wq1b, 1536 * 512);
    cast_bf_kernel<<<256, 256, 0, stream>>>(wproj1, wp1b, 512 * 512);
    cast_bf_kernel<<<512, 256, 0, stream>>>(wqkv2 + (size_t)512 * 512, wkv2b, 1024 * 512);

    // ---- layer 1 (full) ----
    concat_kernel<<<8194, 256, 0, stream>>>(x, cls, h0, NTOK * CDIM);
    ln_kernel<<<NTOK, 256, 0, stream>>>(h0, ln_g1, bfbuf);
    gemm_bf16<<<dim3(33, 12), 256, 0, stream>>>(bfbuf, wq1b, nullptr, nullptr, qkv, NTOK, 1536);
    flash1_mfma<<<dim3(65, 8), 256, 0, stream>>>(qkv, attn);
    convres_kernel<<<8194, 256, 0, stream>>>(qkv, resk1, attn, bfbuf);
    gemm_bf16<<<dim3(33, 4), 256, 0, stream>>>(bfbuf, wp1b, h0, bproj1, h1, NTOK, 512);

    // ---- layer 2 (only what token 0 needs) ----
    ln_kernel<<<NTOK, 256, 0, stream>>>(h1, ln_g2, bfbuf);
    gemm_bf16<<<dim3(33, 8), 256, 0, stream>>>(bfbuf, wkv2b, nullptr, nullptr, kv2, NTOK, 1024);
    qrow_kernel<<<512, 64, 0, stream>>>(bfbuf, wqkv2, q2);
    srow_kernel<<<dim3(17, 8), 256, 0, stream>>>(q2, kv2, srow);
    softmax_row<<<8, 256, 0, stream>>>(srow, Lrow);
    pv_row<<<512, 256, 0, stream>>>(srow, kv2, Lrow, o2);
    conv0_kernel<<<1, 512, 0, stream>>>(kv2, resk2, o2);
    final_kernel<<<1, 512, 0, stream>>>(h1, o2, wproj2, bproj2, fc_g, out);
}

// Round 8
// 440.864 us; speedup vs baseline: 5.0860x; 1.1016x over previous
//
#include <hip/hip_runtime.h>
#include <math.h>

#define NTOK 4097
#define CDIM 512
#define EPS_LN 1e-5f

typedef float f32x4 __attribute__((ext_vector_type(4)));
typedef __bf16 bf16x8 __attribute__((ext_vector_type(8)));

__device__ inline unsigned short f2bf(float f){
    union { float f; unsigned u; } c; c.f = f;
    unsigned u = c.u;
    unsigned r = (u + 0x7fffu + ((u >> 16) & 1u)) >> 16;
    return (unsigned short)r;
}
__device__ inline float bf2f(unsigned short b){
    union { unsigned u; float f; } c; c.u = ((unsigned)b) << 16;
    return c.f;
}
__device__ inline unsigned cvt_pk_bf16(float lo, float hi){
    unsigned r;
    asm("v_cvt_pk_bf16_f32 %0, %1, %2" : "=v"(r) : "v"(lo), "v"(hi));
    return r;
}

// ---------------- concat: h0 = [cls; x] ----------------
__global__ void concat_kernel(const float* __restrict__ x, const float* __restrict__ cls,
                              float* __restrict__ h0, int total){
    int idx = blockIdx.x * 256 + threadIdx.x;
    if (idx >= total) return;
    int n = idx >> 9;
    int c = idx & 511;
    h0[idx] = (n == 0) ? cls[c] : x[(size_t)(n - 1) * CDIM + c];
}

// ---------------- cast f32 -> bf16 ----------------
__global__ void cast_bf_kernel(const float* __restrict__ src, unsigned short* __restrict__ dst, int n){
    int i = (blockIdx.x * 256 + threadIdx.x) * 4;
    if (i >= n) return;
    float4 v = *(const float4*)(src + i);
    ushort4 o;
    o.x = f2bf(v.x); o.y = f2bf(v.y); o.z = f2bf(v.z); o.w = f2bf(v.w);
    *(ushort4*)(dst + i) = o;
}

// ---------------- layernorm (no bias) -> bf16 out ----------------
__global__ __launch_bounds__(256) void ln_kernel(const float* __restrict__ in,
                                                 const float* __restrict__ g,
                                                 unsigned short* __restrict__ out){
    int n = blockIdx.x;
    const float* row = in + (size_t)n * CDIM;
    int t = threadIdx.x;
    float x0 = row[t], x1 = row[t + 256];
    float s = x0 + x1, q = x0 * x0 + x1 * x1;
    for (int o = 32; o > 0; o >>= 1) { s += __shfl_down(s, o); q += __shfl_down(q, o); }
    __shared__ float rs[4], rq[4], mv[2];
    int wid = t >> 6;
    if ((t & 63) == 0) { rs[wid] = s; rq[wid] = q; }
    __syncthreads();
    if (t == 0) {
        float S = rs[0] + rs[1] + rs[2] + rs[3];
        float Q = rq[0] + rq[1] + rq[2] + rq[3];
        float m = S / 512.0f;
        float v = Q / 512.0f - m * m;
        mv[0] = m; mv[1] = rsqrtf(v + EPS_LN);
    }
    __syncthreads();
    float m = mv[0], r = mv[1];
    unsigned short* orow = out + (size_t)n * CDIM;
    orow[t]       = f2bf((x0 - m) * r * g[t]);
    orow[t + 256] = f2bf((x1 - m) * r * g[t + 256]);
}

// ---------------- bf16 MFMA GEMM: C[M,N] = A[M,512]*B[N,512]^T (+bias)(+resid) ----
// obf!=0 -> bf16 output (no bias/resid support needed there), else fp32 out.
__global__ __launch_bounds__(256) void gemm_bf16(const unsigned short* __restrict__ A,
                                                 const unsigned short* __restrict__ B,
                                                 const float* __restrict__ resid,
                                                 const float* __restrict__ bias,
                                                 void* __restrict__ Cout, int M, int N, int obf){
    __shared__ unsigned short As[128][72];
    __shared__ unsigned short Bs[128][72];
    int t = threadIdx.x;
    int wave = t >> 6, lane = t & 63;
    int wr = wave >> 1, wc = wave & 1;
    int bm = blockIdx.x, bn = blockIdx.y;
    f32x4 acc[4][4] = {};
    int lrow = t >> 3;
    int lc8 = (t & 7) * 8;
    for (int k0 = 0; k0 < 512; k0 += 64) {
        __syncthreads();
        #pragma unroll
        for (int i = 0; i < 4; i++) {
            int row = lrow + i * 32;
            int ar = bm * 128 + row; if (ar > M - 1) ar = M - 1;
            int br = bn * 128 + row;
            *(uint4*)(&As[row][lc8]) = *(const uint4*)(A + (size_t)ar * 512 + k0 + lc8);
            *(uint4*)(&Bs[row][lc8]) = *(const uint4*)(B + (size_t)br * 512 + k0 + lc8);
        }
        __syncthreads();
        #pragma unroll
        for (int ks = 0; ks < 2; ks++) {
            bf16x8 af[4], bfr[4];
            #pragma unroll
            for (int mi = 0; mi < 4; mi++)
                af[mi] = *(const bf16x8*)(&As[wr * 64 + mi * 16 + (lane & 15)][ks * 32 + (lane >> 4) * 8]);
            #pragma unroll
            for (int ni = 0; ni < 4; ni++)
                bfr[ni] = *(const bf16x8*)(&Bs[wc * 64 + ni * 16 + (lane & 15)][ks * 32 + (lane >> 4) * 8]);
            #pragma unroll
            for (int mi = 0; mi < 4; mi++)
                #pragma unroll
                for (int ni = 0; ni < 4; ni++)
                    acc[mi][ni] = __builtin_amdgcn_mfma_f32_16x16x32_bf16(af[mi], bfr[ni], acc[mi][ni], 0, 0, 0);
        }
    }
    int n0 = bn * 128 + wc * 64;
    if (obf) {
        unsigned short* C = (unsigned short*)Cout;
        #pragma unroll
        for (int mi = 0; mi < 4; mi++)
            #pragma unroll
            for (int rg = 0; rg < 4; rg++) {
                int m = bm * 128 + wr * 64 + mi * 16 + (lane >> 4) * 4 + rg;
                if (m < M) {
                    unsigned short* crow = C + (size_t)m * N;
                    #pragma unroll
                    for (int ni = 0; ni < 4; ni++)
                        crow[n0 + ni * 16 + (lane & 15)] = f2bf(acc[mi][ni][rg]);
                }
            }
    } else {
        float* C = (float*)Cout;
        #pragma unroll
        for (int mi = 0; mi < 4; mi++)
            #pragma unroll
            for (int rg = 0; rg < 4; rg++) {
                int m = bm * 128 + wr * 64 + mi * 16 + (lane >> 4) * 4 + rg;
                if (m < M) {
                    float* crow = C + (size_t)m * N;
                    const float* rrow = resid ? resid + (size_t)m * N : nullptr;
                    #pragma unroll
                    for (int ni = 0; ni < 4; ni++) {
                        int n = n0 + ni * 16 + (lane & 15);
                        float v = acc[mi][ni][rg];
                        if (bias) v += bias[n];
                        if (rrow) v += rrow[n];
                        crow[n] = v;
                    }
                }
            }
    }
}

// ---------------- layer-1 flash attention, bf16 MFMA, split-K x2 ----------------
// qkvb: bf16 [NTOK][1536]. opart: [2][NTOK][512] unnormalized. ml: [2][8][NTOK][2].
__global__ __launch_bounds__(256) void flash1_mfma(const unsigned short* __restrict__ qkvb,
                                                   float* __restrict__ opart, float* __restrict__ ml){
    __shared__ __align__(16) char smem[24576];
    unsigned short* Qs = (unsigned short*)smem;          // [64 q][64 d] swizzled
    unsigned short* Ks = Qs + 4096;                      // [64 key][64 d]
    unsigned short* Vt = Ks + 4096;                      // [64 d][64 key]
    const int h = blockIdx.y, qb = blockIdx.x, sp = blockIdx.z;
    const int t = threadIdx.x;
    const int wave = t >> 6, lane = t & 63;
    const int g = lane >> 4, q = lane & 15;
    const int rr8 = t >> 3;          // 0..31
    const int dc8 = (t & 7) * 8;     // 0,8,..,56

    // ---- stage Q (raw bf16 copy; 0.125 scale applied at softmax) ----
    #pragma unroll
    for (int pp = 0; pp < 2; pp++) {
        int r = rr8 + pp * 32;
        int tok = qb * 64 + r;
        uint4 qv = make_uint4(0, 0, 0, 0);
        if (tok < NTOK) qv = *(const uint4*)(qkvb + (size_t)tok * 1536 + h * 64 + dc8);
        *(uint4*)((char*)Qs + ((r * 128 + dc8 * 2) ^ ((r & 7) << 4))) = qv;
    }

    f32x4 acco[4] = {};
    float m_run = -INFINITY, l_run = 0.f;
    const int ktbeg = sp * 33;
    const int ktend = sp ? 65 : 33;

    for (int kt = ktbeg; kt < ktend; kt++) {
        __syncthreads();
        #pragma unroll
        for (int pp = 0; pp < 2; pp++) {
            int r = rr8 + pp * 32;
            int tok = kt * 64 + r;
            uint4 kv8 = make_uint4(0, 0, 0, 0);
            uint4 vv8 = make_uint4(0, 0, 0, 0);
            if (tok < NTOK) {
                const unsigned short* base = qkvb + (size_t)tok * 1536 + 512 + h * 64 + dc8;
                kv8 = *(const uint4*)(base);
                vv8 = *(const uint4*)(base + 512);
            }
            *(uint4*)((char*)Ks + ((r * 128 + dc8 * 2) ^ ((r & 7) << 4))) = kv8;
            const unsigned short* vsrc = (const unsigned short*)&vv8;
            #pragma unroll
            for (int e = 0; e < 8; e++) {
                int d = dc8 + e;
                *(unsigned short*)((char*)Vt + ((d * 128 + r * 2) ^ ((d & 7) << 4))) = vsrc[e];
            }
        }
        __syncthreads();

        // ---- S^T = K * Q^T ----
        f32x4 accs[4] = {};
        #pragma unroll
        for (int ks = 0; ks < 2; ks++) {
            int qrow = wave * 16 + q;
            bf16x8 bq = *(const bf16x8*)((char*)Qs + ((qrow * 128 + ks * 64 + g * 16) ^ ((qrow & 7) << 4)));
            #pragma unroll
            for (int mt = 0; mt < 4; mt++) {
                int kr = mt * 16 + q;
                bf16x8 ak = *(const bf16x8*)((char*)Ks + ((kr * 128 + ks * 64 + g * 16) ^ ((kr & 7) << 4)));
                accs[mt] = __builtin_amdgcn_mfma_f32_16x16x32_bf16(ak, bq, accs[mt], 0, 0, 0);
            }
        }

        // ---- online softmax ----
        float pr[4][4];
        float tmax = -INFINITY;
        #pragma unroll
        for (int mt = 0; mt < 4; mt++)
            #pragma unroll
            for (int rg = 0; rg < 4; rg++) {
                float s = accs[mt][rg] * 0.125f;
                if (kt == 64 && (4096 + mt * 16 + g * 4 + rg) >= NTOK) s = -INFINITY;
                pr[mt][rg] = s;
                tmax = fmaxf(tmax, s);
            }
        tmax = fmaxf(tmax, __shfl_xor(tmax, 16));
        tmax = fmaxf(tmax, __shfl_xor(tmax, 32));
        float mn = fmaxf(m_run, tmax);
        float alpha = __expf(m_run - mn);
        float psum = 0.f;
        #pragma unroll
        for (int mt = 0; mt < 4; mt++)
            #pragma unroll
            for (int rg = 0; rg < 4; rg++) {
                float pv = __expf(pr[mt][rg] - mn);
                pr[mt][rg] = pv;
                psum += pv;
            }
        psum += __shfl_xor(psum, 16);
        psum += __shfl_xor(psum, 32);
        l_run = l_run * alpha + psum;
        m_run = mn;
        #pragma unroll
        for (int mt = 0; mt < 4; mt++)
            #pragma unroll
            for (int rg = 0; rg < 4; rg++)
                acco[mt][rg] *= alpha;

        unsigned pk[4][2];
        #pragma unroll
        for (int mt = 0; mt < 4; mt++) {
            pk[mt][0] = cvt_pk_bf16(pr[mt][0], pr[mt][1]);
            pk[mt][1] = cvt_pk_bf16(pr[mt][2], pr[mt][3]);
        }

        // ---- O^T += V^T * P^T ----
        #pragma unroll
        for (int ks = 0; ks < 2; ks++) {
            union { unsigned w[4]; bf16x8 v; } bp;
            #pragma unroll
            for (int sh = 0; sh < 2; sh++)
                #pragma unroll
                for (int rp = 0; rp < 2; rp++) {
                    int src = ((g & 1) * 2 + sh) * 16 + q;
                    unsigned r0 = __shfl(pk[2 * ks + 0][rp], src);
                    unsigned r1 = __shfl(pk[2 * ks + 1][rp], src);
                    bp.w[sh * 2 + rp] = (g < 2) ? r0 : r1;
                }
            #pragma unroll
            for (int mt = 0; mt < 4; mt++) {
                int dr = mt * 16 + q;
                bf16x8 av = *(const bf16x8*)((char*)Vt + ((dr * 128 + ks * 64 + g * 16) ^ ((dr & 7) << 4)));
                acco[mt] = __builtin_amdgcn_mfma_f32_16x16x32_bf16(av, bp.v, acco[mt], 0, 0, 0);
            }
        }
    }

    // ---- epilogue: store unnormalized O^T + (m,l) ----
    __syncthreads();
    {
        int tok_ml = qb * 64 + wave * 16 + q;
        if (g == 0 && tok_ml < NTOK) {
            float* mlp = ml + ((size_t)(sp * 8 + h) * NTOK + tok_ml) * 2;
            mlp[0] = m_run;
            mlp[1] = l_run;
        }
    }
    float* ob = (float*)smem + wave * 16 * 68;
    #pragma unroll
    for (int mt = 0; mt < 4; mt++)
        #pragma unroll
        for (int rg = 0; rg < 4; rg++)
            ob[q * 68 + mt * 16 + g * 4 + rg] = acco[mt][rg];
    __syncthreads();
    {
        float* outp = opart + (size_t)sp * NTOK * 512;
        int ql = lane >> 2;
        int tok = qb * 64 + wave * 16 + ql;
        #pragma unroll
        for (int i = 0; i < 4; i++) {
            int c = (lane & 3) + i * 4;
            if (tok < NTOK)
                *(float4*)(outp + (size_t)tok * 512 + h * 64 + c * 4) = *(const float4*)(ob + ql * 68 + c * 4);
        }
    }
}

// ---------------- combine the two K-splits ----------------
__global__ void flash_combine(const float* __restrict__ opart, const float* __restrict__ ml,
                              float* __restrict__ attn){
    int idx = blockIdx.x * 256 + threadIdx.x;
    if (idx >= NTOK * CDIM) return;
    int tok = idx >> 9, h = (idx & 511) >> 6;
    const float* ml0 = ml + ((size_t)h * NTOK + tok) * 2;
    const float* ml1 = ml + ((size_t)(8 + h) * NTOK + tok) * 2;
    float m0 = ml0[0], l0 = ml0[1];
    float m1 = ml1[0], l1 = ml1[1];
    float M = fmaxf(m0, m1);
    float a0 = __expf(m0 - M), a1 = __expf(m1 - M);
    float o0 = opart[idx];
    float o1 = opart[(size_t)NTOK * 512 + idx];
    attn[idx] = (o0 * a0 + o1 * a1) / (l0 * a0 + l1 * a1);
}

// ---------------- layer-1 depthwise conv residual add -> bf16 out ----------------
__global__ void convres_kernel(const unsigned short* __restrict__ qkvb, const float* __restrict__ rk,
                               const float* __restrict__ attn, unsigned short* __restrict__ attn_bf){
    int idx = blockIdx.x * 256 + threadIdx.x;
    if (idx >= NTOK * CDIM) return;
    int n = idx >> 9, hd = idx & 511, h = hd >> 6;
    float a = attn[idx];
    const float* kr = rk + h * 33;
    #pragma unroll
    for (int k = 0; k < 33; k++) {
        int mm = n + k - 16;
        if (mm >= 0 && mm < NTOK)
            a += bf2f(qkvb[(size_t)mm * 1536 + 1024 + hd]) * kr[k];
    }
    attn_bf[idx] = f2bf(a);
}

// ---------------- layer 2: q row 0 (ln2 in bf16) ----------------
__global__ void qrow_kernel(const unsigned short* __restrict__ ln2b, const float* __restrict__ wqkv,
                            float* __restrict__ q2){
    int j = blockIdx.x;
    int lane = threadIdx.x;
    const float* w = wqkv + (size_t)j * 512;
    float s = 0.f;
    for (int k = lane; k < 512; k += 64) s += bf2f(ln2b[k]) * w[k];
    for (int o = 32; o > 0; o >>= 1) s += __shfl_down(s, o);
    if (lane == 0) q2[j] = s;
}

// ---------------- layer 2: score row 0 (kv2 bf16) ----------------
__global__ void srow_kernel(const float* __restrict__ q2, const unsigned short* __restrict__ kv2b,
                            float* __restrict__ srow){
    int mm = blockIdx.x * 256 + threadIdx.x;
    int h = blockIdx.y;
    if (mm >= NTOK) return;
    const float* q = q2 + h * 64;
    const unsigned short* k = kv2b + (size_t)mm * 1024 + h * 64;
    float s = 0.f;
    #pragma unroll
    for (int d = 0; d < 64; d++) s += q[d] * bf2f(k[d]);
    srow[(size_t)h * NTOK + mm] = s * 0.125f;
}

// ---------------- layer 2: softmax over score row ----------------
__global__ __launch_bounds__(256) void softmax_row(float* __restrict__ srow, float* __restrict__ Lout){
    int h = blockIdx.x, t = threadIdx.x;
    float* s = srow + (size_t)h * NTOK;
    __shared__ float red[4];
    float mx = -INFINITY;
    for (int i = t; i < NTOK; i += 256) mx = fmaxf(mx, s[i]);
    for (int o = 32; o > 0; o >>= 1) mx = fmaxf(mx, __shfl_xor(mx, o));
    if ((t & 63) == 0) red[t >> 6] = mx;
    __syncthreads();
    mx = fmaxf(fmaxf(red[0], red[1]), fmaxf(red[2], red[3]));
    __syncthreads();
    float sum = 0.f;
    for (int i = t; i < NTOK; i += 256) { float p = __expf(s[i] - mx); s[i] = p; sum += p; }
    for (int o = 32; o > 0; o >>= 1) sum += __shfl_xor(sum, o);
    if ((t & 63) == 0) red[t >> 6] = sum;
    __syncthreads();
    if (t == 0) Lout[h] = red[0] + red[1] + red[2] + red[3];
}

// ---------------- layer 2: o2[hd] = sum_m p[h][m]*v2[m][hd] / L[h] ----------------
__global__ __launch_bounds__(256) void pv_row(const float* __restrict__ srow, const unsigned short* __restrict__ kv2b,
                                              const float* __restrict__ L, float* __restrict__ o2){
    int hd = blockIdx.x;
    int h = hd >> 6;
    int t = threadIdx.x;
    const float* p = srow + (size_t)h * NTOK;
    const unsigned short* v = kv2b + 512 + hd;
    float s = 0.f;
    for (int i = t; i < NTOK; i += 256) s += p[i] * bf2f(v[(size_t)i * 1024]);
    for (int o = 32; o > 0; o >>= 1) s += __shfl_down(s, o);
    __shared__ float red[4];
    if ((t & 63) == 0) red[t >> 6] = s;
    __syncthreads();
    if (t == 0) o2[hd] = (red[0] + red[1] + red[2] + red[3]) / L[h];
}

// ---------------- layer 2: conv at position 0 ----------------
__global__ void conv0_kernel(const unsigned short* __restrict__ kv2b, const float* __restrict__ rk,
                             float* __restrict__ o2){
    int hd = threadIdx.x;
    int h = hd >> 6;
    float a = o2[hd];
    #pragma unroll
    for (int k = 16; k < 33; k++)
        a += bf2f(kv2b[(size_t)(k - 16) * 1024 + 512 + hd]) * rk[h * 33 + k];
    o2[hd] = a;
}

// ---------------- final: proj row 0 + residual + layernorm ----------------
__global__ __launch_bounds__(512) void final_kernel(const float* __restrict__ h1, const float* __restrict__ o2,
                                                    const float* __restrict__ wproj, const float* __restrict__ bproj,
                                                    const float* __restrict__ fcg, float* __restrict__ out){
    __shared__ float ov[512];
    __shared__ float red_s[8], red_q[8], mv[2];
    int t = threadIdx.x;
    ov[t] = o2[t];
    __syncthreads();
    const float* w = wproj + (size_t)t * 512;
    float acc = h1[t] + bproj[t];
    for (int k = 0; k < 512; k++) acc += ov[k] * w[k];
    float s = acc, q = acc * acc;
    for (int o = 32; o > 0; o >>= 1) { s += __shfl_down(s, o); q += __shfl_down(q, o); }
    if ((t & 63) == 0) { red_s[t >> 6] = s; red_q[t >> 6] = q; }
    __syncthreads();
    if (t == 0) {
        float S = 0.f, Q = 0.f;
        for (int i = 0; i < 8; i++) { S += red_s[i]; Q += red_q[i]; }
        float m = S / 512.0f;
        float v = Q / 512.0f - m * m;
        mv[0] = m; mv[1] = rsqrtf(v + EPS_LN);
    }
    __syncthreads();
    out[t] = (acc - mv[0]) * mv[1] * fcg[t];
}

extern "C" void kernel_launch(void* const* d_in, const int* in_sizes, int n_in,
                              void* d_out, int out_size, void* d_ws, size_t ws_size,
                              hipStream_t stream){
    const float* x      = (const float*)d_in[0];
    const float* cls    = (const float*)d_in[1];
    const float* ln_g1  = (const float*)d_in[2];
    const float* wqkv1  = (const float*)d_in[3];
    const float* wproj1 = (const float*)d_in[4];
    const float* bproj1 = (const float*)d_in[5];
    const float* resk1  = (const float*)d_in[6];
    const float* ln_g2  = (const float*)d_in[7];
    const float* wqkv2  = (const float*)d_in[8];
    const float* wproj2 = (const float*)d_in[9];
    const float* bproj2 = (const float*)d_in[10];
    const float* resk2  = (const float*)d_in[11];
    const float* fc_g   = (const float*)d_in[12];
    float* out = (float*)d_out;
    float* ws  = (float*)d_ws;

    const size_t NC = (size_t)NTOK * 512;           // 2,097,664
    float* h0    = ws;                              // NC f32
    unsigned short* qkvb = (unsigned short*)(h0 + NC);        // NTOK*1536 bf16 (= NC*1.5 f32)
    float* attn  = h0 + NC + (NC * 3) / 2;          // NC f32  (alias: Opart split 0)
    float* h1    = attn + NC;                       // NC f32  (alias: Opart split 1)
    float* opart = attn;                            // [2][NTOK][512]
    float* sm    = h1 + NC;                         // small scratch
    float* q2    = sm;                              // 512
    float* o2    = sm + 512;                        // 512
    float* Lrow  = sm + 1024;                       // 8
    float* srow  = sm + 2048;                       // 8*NTOK
    float* ml    = sm + 40960;                      // 2*8*NTOK*2 = 131,104 f32
    unsigned short* bfbuf = (unsigned short*)(ml + 131104);   // NC bf16
    unsigned short* wq1b  = bfbuf + NC;             // 1536*512
    unsigned short* wp1b  = wq1b + 1536 * 512;      // 512*512
    unsigned short* wkv2b = wp1b + 512 * 512;       // 1024*512
    unsigned short* kv2b  = qkvb;                   // layer-2 alias (qkvb dead after convres)

    // ---- one-time weight casts ----
    cast_bf_kernel<<<768, 256, 0, stream>>>(wqkv1, wq1b, 1536 * 512);
    cast_bf_kernel<<<256, 256, 0, stream>>>(wproj1, wp1b, 512 * 512);
    cast_bf_kernel<<<512, 256, 0, stream>>>(wqkv2 + (size_t)512 * 512, wkv2b, 1024 * 512);

    // ---- layer 1 (full) ----
    concat_kernel<<<8194, 256, 0, stream>>>(x, cls, h0, NTOK * CDIM);
    ln_kernel<<<NTOK, 256, 0, stream>>>(h0, ln_g1, bfbuf);
    gemm_bf16<<<dim3(33, 12), 256, 0, stream>>>(bfbuf, wq1b, nullptr, nullptr, qkvb, NTOK, 1536, 1);
    flash1_mfma<<<dim3(65, 8, 2), 256, 0, stream>>>(qkvb, opart, ml);
    flash_combine<<<8194, 256, 0, stream>>>(opart, ml, attn);
    convres_kernel<<<8194, 256, 0, stream>>>(qkvb, resk1, attn, bfbuf);
    gemm_bf16<<<dim3(33, 4), 256, 0, stream>>>(bfbuf, wp1b, h0, bproj1, h1, NTOK, 512, 0);

    // ---- layer 2 (only what token 0 needs) ----
    ln_kernel<<<NTOK, 256, 0, stream>>>(h1, ln_g2, bfbuf);
    gemm_bf16<<<dim3(33, 8), 256, 0, stream>>>(bfbuf, wkv2b, nullptr, nullptr, kv2b, NTOK, 1024, 1);
    qrow_kernel<<<512, 64, 0, stream>>>(bfbuf, wqkv2, q2);
    srow_kernel<<<dim3(17, 8), 256, 0, stream>>>(q2, kv2b, srow);
    softmax_row<<<8, 256, 0, stream>>>(srow, Lrow);
    pv_row<<<512, 256, 0, stream>>>(srow, kv2b, Lrow, o2);
    conv0_kernel<<<1, 512, 0, stream>>>(kv2b, resk2, o2);
    final_kernel<<<1, 512, 0, stream>>>(h1, o2, wproj2, bproj2, fc_g, out);
}

// Round 11
// 380.590 us; speedup vs baseline: 5.8915x; 1.1584x over previous
//
#include <hip/hip_runtime.h>
#include <math.h>

#define NTOK 4097
#define CDIM 512
#define EPS_LN 1e-5f

typedef float f32x4 __attribute__((ext_vector_type(4)));
typedef __bf16 bf16x8 __attribute__((ext_vector_type(8)));

__device__ inline unsigned short f2bf(float f){
    union { float f; unsigned u; } c; c.f = f;
    unsigned u = c.u;
    unsigned r = (u + 0x7fffu + ((u >> 16) & 1u)) >> 16;
    return (unsigned short)r;
}
__device__ inline float bf2f(unsigned short b){
    union { unsigned u; float f; } c; c.u = ((unsigned)b) << 16;
    return c.f;
}
__device__ inline unsigned cvt_pk_bf16(float lo, float hi){
    unsigned r;
    asm("v_cvt_pk_bf16_f32 %0, %1, %2" : "=v"(r) : "v"(lo), "v"(hi));
    return r;
}

// ---------------- concat: h0 = [cls; x] ----------------
__global__ void concat_kernel(const float* __restrict__ x, const float* __restrict__ cls,
                              float* __restrict__ h0, int total){
    int idx = blockIdx.x * 256 + threadIdx.x;
    if (idx >= total) return;
    int n = idx >> 9;
    int c = idx & 511;
    h0[idx] = (n == 0) ? cls[c] : x[(size_t)(n - 1) * CDIM + c];
}

// ---------------- cast f32 -> bf16 ----------------
__global__ void cast_bf_kernel(const float* __restrict__ src, unsigned short* __restrict__ dst, int n){
    int i = (blockIdx.x * 256 + threadIdx.x) * 4;
    if (i >= n) return;
    float4 v = *(const float4*)(src + i);
    ushort4 o;
    o.x = f2bf(v.x); o.y = f2bf(v.y); o.z = f2bf(v.z); o.w = f2bf(v.w);
    *(ushort4*)(dst + i) = o;
}

// ---------------- layernorm (no bias) -> bf16 out ----------------
__global__ __launch_bounds__(256) void ln_kernel(const float* __restrict__ in,
                                                 const float* __restrict__ g,
                                                 unsigned short* __restrict__ out){
    int n = blockIdx.x;
    const float* row = in + (size_t)n * CDIM;
    int t = threadIdx.x;
    float x0 = row[t], x1 = row[t + 256];
    float s = x0 + x1, q = x0 * x0 + x1 * x1;
    for (int o = 32; o > 0; o >>= 1) { s += __shfl_down(s, o); q += __shfl_down(q, o); }
    __shared__ float rs[4], rq[4], mv[2];
    int wid = t >> 6;
    if ((t & 63) == 0) { rs[wid] = s; rq[wid] = q; }
    __syncthreads();
    if (t == 0) {
        float S = rs[0] + rs[1] + rs[2] + rs[3];
        float Q = rq[0] + rq[1] + rq[2] + rq[3];
        float m = S / 512.0f;
        float v = Q / 512.0f - m * m;
        mv[0] = m; mv[1] = rsqrtf(v + EPS_LN);
    }
    __syncthreads();
    float m = mv[0], r = mv[1];
    unsigned short* orow = out + (size_t)n * CDIM;
    orow[t]       = f2bf((x0 - m) * r * g[t]);
    orow[t + 256] = f2bf((x1 - m) * r * g[t + 256]);
}

// ---------------- bf16 MFMA GEMM: C[M,N] = A[M,512]*B[N,512]^T (+bias)(+resid) ----
__global__ __launch_bounds__(256) void gemm_bf16(const unsigned short* __restrict__ A,
                                                 const unsigned short* __restrict__ B,
                                                 const float* __restrict__ resid,
                                                 const float* __restrict__ bias,
                                                 void* __restrict__ Cout, int M, int N, int obf){
    __shared__ unsigned short As[128][72];
    __shared__ unsigned short Bs[128][72];
    int t = threadIdx.x;
    int wave = t >> 6, lane = t & 63;
    int wr = wave >> 1, wc = wave & 1;
    int bm = blockIdx.x, bn = blockIdx.y;
    f32x4 acc[4][4] = {};
    int lrow = t >> 3;
    int lc8 = (t & 7) * 8;
    for (int k0 = 0; k0 < 512; k0 += 64) {
        __syncthreads();
        #pragma unroll
        for (int i = 0; i < 4; i++) {
            int row = lrow + i * 32;
            int ar = bm * 128 + row; if (ar > M - 1) ar = M - 1;
            int br = bn * 128 + row;
            *(uint4*)(&As[row][lc8]) = *(const uint4*)(A + (size_t)ar * 512 + k0 + lc8);
            *(uint4*)(&Bs[row][lc8]) = *(const uint4*)(B + (size_t)br * 512 + k0 + lc8);
        }
        __syncthreads();
        #pragma unroll
        for (int ks = 0; ks < 2; ks++) {
            bf16x8 af[4], bfr[4];
            #pragma unroll
            for (int mi = 0; mi < 4; mi++)
                af[mi] = *(const bf16x8*)(&As[wr * 64 + mi * 16 + (lane & 15)][ks * 32 + (lane >> 4) * 8]);
            #pragma unroll
            for (int ni = 0; ni < 4; ni++)
                bfr[ni] = *(const bf16x8*)(&Bs[wc * 64 + ni * 16 + (lane & 15)][ks * 32 + (lane >> 4) * 8]);
            #pragma unroll
            for (int mi = 0; mi < 4; mi++)
                #pragma unroll
                for (int ni = 0; ni < 4; ni++)
                    acc[mi][ni] = __builtin_amdgcn_mfma_f32_16x16x32_bf16(af[mi], bfr[ni], acc[mi][ni], 0, 0, 0);
        }
    }
    int n0 = bn * 128 + wc * 64;
    if (obf) {
        unsigned short* C = (unsigned short*)Cout;
        #pragma unroll
        for (int mi = 0; mi < 4; mi++)
            #pragma unroll
            for (int rg = 0; rg < 4; rg++) {
                int m = bm * 128 + wr * 64 + mi * 16 + (lane >> 4) * 4 + rg;
                if (m < M) {
                    unsigned short* crow = C + (size_t)m * N;
                    #pragma unroll
                    for (int ni = 0; ni < 4; ni++)
                        crow[n0 + ni * 16 + (lane & 15)] = f2bf(acc[mi][ni][rg]);
                }
            }
    } else {
        float* C = (float*)Cout;
        #pragma unroll
        for (int mi = 0; mi < 4; mi++)
            #pragma unroll
            for (int rg = 0; rg < 4; rg++) {
                int m = bm * 128 + wr * 64 + mi * 16 + (lane >> 4) * 4 + rg;
                if (m < M) {
                    float* crow = C + (size_t)m * N;
                    const float* rrow = resid ? resid + (size_t)m * N : nullptr;
                    #pragma unroll
                    for (int ni = 0; ni < 4; ni++) {
                        int n = n0 + ni * 16 + (lane & 15);
                        float v = acc[mi][ni][rg];
                        if (bias) v += bias[n];
                        if (rrow) v += rrow[n];
                        crow[n] = v;
                    }
                }
            }
    }
}

// ---------------- layer-1 flash attention, bf16 MFMA, split-K x2 ----------------
// V swizzle: ((d&7)^((d>>3)&7))<<4 -> conflict-free transposed scatter (was 8-way).
__global__ __launch_bounds__(256) void flash1_mfma(const unsigned short* __restrict__ qkvb,
                                                   float* __restrict__ opart, float* __restrict__ ml){
    __shared__ __align__(16) char smem[24576];
    unsigned short* Qs = (unsigned short*)smem;          // [64 q][64 d] swizzled
    unsigned short* Ks = Qs + 4096;                      // [64 key][64 d]
    unsigned short* Vt = Ks + 4096;                      // [64 d][64 key]
    const int h = blockIdx.y, qb = blockIdx.x, sp = blockIdx.z;
    const int t = threadIdx.x;
    const int wave = t >> 6, lane = t & 63;
    const int g = lane >> 4, q = lane & 15;
    const int rr8 = t >> 3;          // 0..31
    const int dc8 = (t & 7) * 8;     // 0,8,..,56

    // ---- stage Q (raw bf16 copy; 0.125 scale applied at softmax) ----
    #pragma unroll
    for (int pp = 0; pp < 2; pp++) {
        int r = rr8 + pp * 32;
        int tok = qb * 64 + r;
        uint4 qv = make_uint4(0, 0, 0, 0);
        if (tok < NTOK) qv = *(const uint4*)(qkvb + (size_t)tok * 1536 + h * 64 + dc8);
        *(uint4*)((char*)Qs + ((r * 128 + dc8 * 2) ^ ((r & 7) << 4))) = qv;
    }

    f32x4 acco[4] = {};
    float m_run = -INFINITY, l_run = 0.f;
    const int ktbeg = sp * 33;
    const int ktend = sp ? 65 : 33;

    for (int kt = ktbeg; kt < ktend; kt++) {
        __syncthreads();
        #pragma unroll
        for (int pp = 0; pp < 2; pp++) {
            int r = rr8 + pp * 32;
            int tok = kt * 64 + r;
            uint4 kv8 = make_uint4(0, 0, 0, 0);
            uint4 vv8 = make_uint4(0, 0, 0, 0);
            if (tok < NTOK) {
                const unsigned short* base = qkvb + (size_t)tok * 1536 + 512 + h * 64 + dc8;
                kv8 = *(const uint4*)(base);
                vv8 = *(const uint4*)(base + 512);
            }
            *(uint4*)((char*)Ks + ((r * 128 + dc8 * 2) ^ ((r & 7) << 4))) = kv8;
            const unsigned short* vsrc = (const unsigned short*)&vv8;
            #pragma unroll
            for (int e = 0; e < 8; e++) {
                int d = dc8 + e;
                *(unsigned short*)((char*)Vt + ((d * 128 + r * 2) ^ (((d & 7) ^ ((d >> 3) & 7)) << 4))) = vsrc[e];
            }
        }
        __syncthreads();

        // ---- S^T = K * Q^T ----
        f32x4 accs[4] = {};
        #pragma unroll
        for (int ks = 0; ks < 2; ks++) {
            int qrow = wave * 16 + q;
            bf16x8 bq = *(const bf16x8*)((char*)Qs + ((qrow * 128 + ks * 64 + g * 16) ^ ((qrow & 7) << 4)));
            #pragma unroll
            for (int mt = 0; mt < 4; mt++) {
                int kr = mt * 16 + q;
                bf16x8 ak = *(const bf16x8*)((char*)Ks + ((kr * 128 + ks * 64 + g * 16) ^ ((kr & 7) << 4)));
                accs[mt] = __builtin_amdgcn_mfma_f32_16x16x32_bf16(ak, bq, accs[mt], 0, 0, 0);
            }
        }

        // ---- online softmax ----
        float pr[4][4];
        float tmax = -INFINITY;
        #pragma unroll
        for (int mt = 0; mt < 4; mt++)
            #pragma unroll
            for (int rg = 0; rg < 4; rg++) {
                float s = accs[mt][rg] * 0.125f;
                if (kt == 64 && (4096 + mt * 16 + g * 4 + rg) >= NTOK) s = -INFINITY;
                pr[mt][rg] = s;
                tmax = fmaxf(tmax, s);
            }
        tmax = fmaxf(tmax, __shfl_xor(tmax, 16));
        tmax = fmaxf(tmax, __shfl_xor(tmax, 32));
        float mn = fmaxf(m_run, tmax);
        float alpha = __expf(m_run - mn);
        float psum = 0.f;
        #pragma unroll
        for (int mt = 0; mt < 4; mt++)
            #pragma unroll
            for (int rg = 0; rg < 4; rg++) {
                float pv = __expf(pr[mt][rg] - mn);
                pr[mt][rg] = pv;
                psum += pv;
            }
        psum += __shfl_xor(psum, 16);
        psum += __shfl_xor(psum, 32);
        l_run = l_run * alpha + psum;
        m_run = mn;
        #pragma unroll
        for (int mt = 0; mt < 4; mt++)
            #pragma unroll
            for (int rg = 0; rg < 4; rg++)
                acco[mt][rg] *= alpha;

        unsigned pk[4][2];
        #pragma unroll
        for (int mt = 0; mt < 4; mt++) {
            pk[mt][0] = cvt_pk_bf16(pr[mt][0], pr[mt][1]);
            pk[mt][1] = cvt_pk_bf16(pr[mt][2], pr[mt][3]);
        }

        // ---- O^T += V^T * P^T ----
        #pragma unroll
        for (int ks = 0; ks < 2; ks++) {
            union { unsigned w[4]; bf16x8 v; } bp;
            #pragma unroll
            for (int sh = 0; sh < 2; sh++)
                #pragma unroll
                for (int rp = 0; rp < 2; rp++) {
                    int src = ((g & 1) * 2 + sh) * 16 + q;
                    unsigned r0 = __shfl(pk[2 * ks + 0][rp], src);
                    unsigned r1 = __shfl(pk[2 * ks + 1][rp], src);
                    bp.w[sh * 2 + rp] = (g < 2) ? r0 : r1;
                }
            #pragma unroll
            for (int mt = 0; mt < 4; mt++) {
                int dr = mt * 16 + q;
                bf16x8 av = *(const bf16x8*)((char*)Vt + ((dr * 128 + ks * 64 + g * 16) ^ (((dr & 7) ^ ((dr >> 3) & 7)) << 4)));
                acco[mt] = __builtin_amdgcn_mfma_f32_16x16x32_bf16(av, bp.v, acco[mt], 0, 0, 0);
            }
        }
    }

    // ---- epilogue: store unnormalized O^T + (m,l) ----
    __syncthreads();
    {
        int tok_ml = qb * 64 + wave * 16 + q;
        if (g == 0 && tok_ml < NTOK) {
            float* mlp = ml + ((size_t)(sp * 8 + h) * NTOK + tok_ml) * 2;
            mlp[0] = m_run;
            mlp[1] = l_run;
        }
    }
    float* ob = (float*)smem + wave * 16 * 68;
    #pragma unroll
    for (int mt = 0; mt < 4; mt++)
        #pragma unroll
        for (int rg = 0; rg < 4; rg++)
            ob[q * 68 + mt * 16 + g * 4 + rg] = acco[mt][rg];
    __syncthreads();
    {
        float* outp = opart + (size_t)sp * NTOK * 512;
        int ql = lane >> 2;
        int tok = qb * 64 + wave * 16 + ql;
        #pragma unroll
        for (int i = 0; i < 4; i++) {
            int c = (lane & 3) + i * 4;
            if (tok < NTOK)
                *(float4*)(outp + (size_t)tok * 512 + h * 64 + c * 4) = *(const float4*)(ob + ql * 68 + c * 4);
        }
    }
}

// ---------------- fused: split-K combine + depthwise conv residual -> bf16 out ----------------
__global__ void convres_kernel(const unsigned short* __restrict__ qkvb, const float* __restrict__ rk,
                               const float* __restrict__ opart, const float* __restrict__ ml,
                               unsigned short* __restrict__ attn_bf){
    int idx = blockIdx.x * 256 + threadIdx.x;
    if (idx >= NTOK * CDIM) return;
    int n = idx >> 9, hd = idx & 511, h = hd >> 6;
    // combine the two flash splits
    const float* ml0 = ml + ((size_t)h * NTOK + n) * 2;
    const float* ml1 = ml + ((size_t)(8 + h) * NTOK + n) * 2;
    float m0 = ml0[0], l0 = ml0[1];
    float m1 = ml1[0], l1 = ml1[1];
    float M = fmaxf(m0, m1);
    float a0 = __expf(m0 - M), a1 = __expf(m1 - M);
    float o0 = opart[idx];
    float o1 = opart[(size_t)NTOK * 512 + idx];
    float a = (o0 * a0 + o1 * a1) / (l0 * a0 + l1 * a1);
    // depthwise conv residual
    const float* kr = rk + h * 33;
    #pragma unroll
    for (int k = 0; k < 33; k++) {
        int mm = n + k - 16;
        if (mm >= 0 && mm < NTOK)
            a += bf2f(qkvb[(size_t)mm * 1536 + 1024 + hd]) * kr[k];
    }
    attn_bf[idx] = f2bf(a);
}

// ---------------- layer 2: q row 0 (ln2 in bf16) ----------------
__global__ void qrow_kernel(const unsigned short* __restrict__ ln2b, const float* __restrict__ wqkv,
                            float* __restrict__ q2){
    int j = blockIdx.x;
    int lane = threadIdx.x;
    const float* w = wqkv + (size_t)j * 512;
    float s = 0.f;
    for (int k = lane; k < 512; k += 64) s += bf2f(ln2b[k]) * w[k];
    for (int o = 32; o > 0; o >>= 1) s += __shfl_down(s, o);
    if (lane == 0) q2[j] = s;
}

// ---------------- layer 2: score row 0 (kv2 bf16) ----------------
__global__ void srow_kernel(const float* __restrict__ q2, const unsigned short* __restrict__ kv2b,
                            float* __restrict__ srow){
    int mm = blockIdx.x * 256 + threadIdx.x;
    int h = blockIdx.y;
    if (mm >= NTOK) return;
    const float* q = q2 + h * 64;
    const unsigned short* k = kv2b + (size_t)mm * 1024 + h * 64;
    float s = 0.f;
    #pragma unroll
    for (int d = 0; d < 64; d++) s += q[d] * bf2f(k[d]);
    srow[(size_t)h * NTOK + mm] = s * 0.125f;
}

// ---------------- layer 2: softmax over score row ----------------
__global__ __launch_bounds__(256) void softmax_row(float* __restrict__ srow, float* __restrict__ Lout){
    int h = blockIdx.x, t = threadIdx.x;
    float* s = srow + (size_t)h * NTOK;
    __shared__ float red[4];
    float mx = -INFINITY;
    for (int i = t; i < NTOK; i += 256) mx = fmaxf(mx, s[i]);
    for (int o = 32; o > 0; o >>= 1) mx = fmaxf(mx, __shfl_xor(mx, o));
    if ((t & 63) == 0) red[t >> 6] = mx;
    __syncthreads();
    mx = fmaxf(fmaxf(red[0], red[1]), fmaxf(red[2], red[3]));
    __syncthreads();
    float sum = 0.f;
    for (int i = t; i < NTOK; i += 256) { float p = __expf(s[i] - mx); s[i] = p; sum += p; }
    for (int o = 32; o > 0; o >>= 1) sum += __shfl_xor(sum, o);
    if ((t & 63) == 0) red[t >> 6] = sum;
    __syncthreads();
    if (t == 0) Lout[h] = red[0] + red[1] + red[2] + red[3];
}

// ---------------- layer 2: o2[hd] = sum_m p[h][m]*v2[m][hd] / L[h] ----------------
__global__ __launch_bounds__(256) void pv_row(const float* __restrict__ srow, const unsigned short* __restrict__ kv2b,
                                              const float* __restrict__ L, float* __restrict__ o2){
    int hd = blockIdx.x;
    int h = hd >> 6;
    int t = threadIdx.x;
    const float* p = srow + (size_t)h * NTOK;
    const unsigned short* v = kv2b + 512 + hd;
    float s = 0.f;
    for (int i = t; i < NTOK; i += 256) s += p[i] * bf2f(v[(size_t)i * 1024]);
    for (int o = 32; o > 0; o >>= 1) s += __shfl_down(s, o);
    __shared__ float red[4];
    if ((t & 63) == 0) red[t >> 6] = s;
    __syncthreads();
    if (t == 0) o2[hd] = (red[0] + red[1] + red[2] + red[3]) / L[h];
}

// ---------------- layer 2: conv at position 0 ----------------
__global__ void conv0_kernel(const unsigned short* __restrict__ kv2b, const float* __restrict__ rk,
                             float* __restrict__ o2){
    int hd = threadIdx.x;
    int h = hd >> 6;
    float a = o2[hd];
    #pragma unroll
    for (int k = 16; k < 33; k++)
        a += bf2f(kv2b[(size_t)(k - 16) * 1024 + 512 + hd]) * rk[h * 33 + k];
    o2[hd] = a;
}

// ---------------- final proj row 0 (parallel over 512 outputs) ----------------
__global__ void proj_row(const float* __restrict__ h1, const float* __restrict__ o2,
                         const float* __restrict__ wproj, const float* __restrict__ bproj,
                         float* __restrict__ pvec){
    int j = blockIdx.x;
    int lane = threadIdx.x;
    const float* w = wproj + (size_t)j * 512;
    float s = 0.f;
    for (int k = lane; k < 512; k += 64) s += o2[k] * w[k];
    for (int o = 32; o > 0; o >>= 1) s += __shfl_down(s, o);
    if (lane == 0) pvec[j] = h1[j] + bproj[j] + s;
}

// ---------------- final layernorm ----------------
__global__ __launch_bounds__(512) void ln_final(const float* __restrict__ pvec,
                                                const float* __restrict__ fcg, float* __restrict__ out){
    __shared__ float red_s[8], red_q[8], mv[2];
    int t = threadIdx.x;
    float acc = pvec[t];
    float s = acc, q = acc * acc;
    for (int o = 32; o > 0; o >>= 1) { s += __shfl_down(s, o); q += __shfl_down(q, o); }
    if ((t & 63) == 0) { red_s[t >> 6] = s; red_q[t >> 6] = q; }
    __syncthreads();
    if (t == 0) {
        float S = 0.f, Q = 0.f;
        for (int i = 0; i < 8; i++) { S += red_s[i]; Q += red_q[i]; }
        float m = S / 512.0f;
        float v = Q / 512.0f - m * m;
        mv[0] = m; mv[1] = rsqrtf(v + EPS_LN);
    }
    __syncthreads();
    out[t] = (acc - mv[0]) * mv[1] * fcg[t];
}

extern "C" void kernel_launch(void* const* d_in, const int* in_sizes, int n_in,
                              void* d_out, int out_size, void* d_ws, size_t ws_size,
                              hipStream_t stream){
    const float* x      = (const float*)d_in[0];
    const float* cls    = (const float*)d_in[1];
    const float* ln_g1  = (const float*)d_in[2];
    const float* wqkv1  = (const float*)d_in[3];
    const float* wproj1 = (const float*)d_in[4];
    const float* bproj1 = (const float*)d_in[5];
    const float* resk1  = (const float*)d_in[6];
    const float* ln_g2  = (const float*)d_in[7];
    const float* wqkv2  = (const float*)d_in[8];
    const float* wproj2 = (const float*)d_in[9];
    const float* bproj2 = (const float*)d_in[10];
    const float* resk2  = (const float*)d_in[11];
    const float* fc_g   = (const float*)d_in[12];
    float* out = (float*)d_out;
    float* ws  = (float*)d_ws;

    const size_t NC = (size_t)NTOK * 512;           // 2,097,664
    float* h0    = ws;                              // NC f32
    unsigned short* qkvb = (unsigned short*)(h0 + NC);        // NTOK*1536 bf16
    float* opart = h0 + NC + (NC * 3) / 2;          // [2][NTOK][512] f32 (split 1 doubles as h1 scratch later)
    float* h1    = opart + NC;                      // NC f32 (overwritten by proj AFTER convres consumed opart)
    float* sm    = h1 + NC;                         // small scratch
    float* q2    = sm;                              // 512
    float* o2    = sm + 512;                        // 512
    float* Lrow  = sm + 1024;                       // 8
    float* pvec  = sm + 1536;                       // 512
    float* srow  = sm + 2048;                       // 8*NTOK
    float* ml    = sm + 40960;                      // 2*8*NTOK*2 = 131,104 f32
    unsigned short* bfbuf = (unsigned short*)(ml + 131104);   // NC bf16
    unsigned short* wq1b  = bfbuf + NC;             // 1536*512
    unsigned short* wp1b  = wq1b + 1536 * 512;      // 512*512
    unsigned short* wkv2b = wp1b + 512 * 512;       // 1024*512
    unsigned short* kv2b  = qkvb;                   // layer-2 alias (qkvb dead after convres)

    // ---- one-time weight casts ----
    cast_bf_kernel<<<768, 256, 0, stream>>>(wqkv1, wq1b, 1536 * 512);
    cast_bf_kernel<<<256, 256, 0, stream>>>(wproj1, wp1b, 512 * 512);
    cast_bf_kernel<<<512, 256, 0, stream>>>(wqkv2 + (size_t)512 * 512, wkv2b, 1024 * 512);

    // ---- layer 1 (full) ----
    concat_kernel<<<8194, 256, 0, stream>>>(x, cls, h0, NTOK * CDIM);
    ln_kernel<<<NTOK, 256, 0, stream>>>(h0, ln_g1, bfbuf);
    gemm_bf16<<<dim3(33, 12), 256, 0, stream>>>(bfbuf, wq1b, nullptr, nullptr, qkvb, NTOK, 1536, 1);
    flash1_mfma<<<dim3(65, 8, 2), 256, 0, stream>>>(qkvb, opart, ml);
    convres_kernel<<<8194, 256, 0, stream>>>(qkvb, resk1, opart, ml, bfbuf);
    gemm_bf16<<<dim3(33, 4), 256, 0, stream>>>(bfbuf, wp1b, h0, bproj1, h1, NTOK, 512, 0);

    // ---- layer 2 (only what token 0 needs) ----
    ln_kernel<<<NTOK, 256, 0, stream>>>(h1, ln_g2, bfbuf);
    gemm_bf16<<<dim3(33, 8), 256, 0, stream>>>(bfbuf, wkv2b, nullptr, nullptr, kv2b, NTOK, 1024, 1);
    qrow_kernel<<<512, 64, 0, stream>>>(bfbuf, wqkv2, q2);
    srow_kernel<<<dim3(17, 8), 256, 0, stream>>>(q2, kv2b, srow);
    softmax_row<<<8, 256, 0, stream>>>(srow, Lrow);
    pv_row<<<512, 256, 0, stream>>>(srow, kv2b, Lrow, o2);
    conv0_kernel<<<1, 512, 0, stream>>>(kv2b, resk2, o2);
    proj_row<<<512, 64, 0, stream>>>(h1, o2, wproj2, bproj2, pvec);
    ln_final<<<1, 512, 0, stream>>>(pvec, fc_g, out);
}